// Round 1
// baseline (847.370 us; speedup 1.0000x reference)
//
#include <hip/hip_runtime.h>
#include <math.h>

// ============================================================================
// Round 1: full fp32 implementation, correctness-first.
// Pipeline: fold BN -> point MLP (+ a0 factorization c_m - q_n) -> exact kNN
//           -> per-pair a1/a2 GEMMs + maxpool -> global max -> head c2/c3/c4.
// ============================================================================

#define EPSBN 1e-5f

// ---- ws layout (float offsets) ----
#define W0T_OFF   0         // [3][64]
#define B0_OFF    192
#define W1T_OFF   256       // [64][64]
#define B1_OFF    4352
#define A0XT_OFF  4416      // [3][64]
#define A0FT_OFF  4608      // [64][64]
#define BA0_OFF   8704
#define A1T_OFF   8768      // [64][128]
#define BA1_OFF   16960
#define A2T_OFF   17088     // [128][128]
#define BA2_OFF   33472
#define C2T_OFF   33600     // [256][256]
#define BC2_OFF   99136
#define C3T_OFF   99392     // [256][128]
#define BC3_OFF   132160
#define C4T_OFF   132288    // [128][6]
#define BC4_OFF   133056
#define PTS4_OFF  133120    // [32768] float4 {x,y,z,sq}
#define Q_OFF     264192    // [32768][64]
#define C_OFF     2361344   // [32768][64]
#define IDX_OFF   4458496   // [32768][16] int (batch-local m)
#define LOCAL_OFF 4982784   // [32768][128]
#define GF_OFF    9177088   // [8][128]

// ---------------------------------------------------------------------------
// Kernel 0: fold BN into weights, store transposed (k-major) into ws.
// ---------------------------------------------------------------------------
__device__ __forceinline__ void fold_one(int e, const float* w, const float* b,
    const float* g, const float* t, const float* m, const float* v,
    float* wt, float* bo, int O, int Cfull, int cbeg)
{
    int o = e % O, c = e / O;
    float s = 1.0f;
    if (g) s = g[o] * (1.0f / sqrtf(v[o] + EPSBN));
    wt[c * O + o] = w[o * Cfull + cbeg + c] * s;
    if (c == 0 && bo) {
        float bias = b[o];
        if (g) bias = (bias - m[o]) * s + t[o];
        bo[o] = bias;
    }
}

__global__ __launch_bounds__(256) void fold_kernel(
    const float* c0w, const float* c0b, const float* c0g, const float* c0t, const float* c0m, const float* c0v,
    const float* c1w, const float* c1b, const float* c1g, const float* c1t, const float* c1m, const float* c1v,
    const float* a0w, const float* a0b, const float* a0g, const float* a0t, const float* a0m, const float* a0v,
    const float* a1w, const float* a1b, const float* a1g, const float* a1t, const float* a1m, const float* a1v,
    const float* a2w, const float* a2b, const float* a2g, const float* a2t, const float* a2m, const float* a2v,
    const float* c2w, const float* c2b, const float* c2g, const float* c2t, const float* c2m, const float* c2v,
    const float* c3w, const float* c3b, const float* c3g, const float* c3t, const float* c3m, const float* c3v,
    const float* c4w, const float* c4b,
    float* ws)
{
    int e = blockIdx.x * 256 + threadIdx.x;
    if (e < 192)        { fold_one(e,          c0w, c0b, c0g, c0t, c0m, c0v, ws + W0T_OFF,  ws + B0_OFF,  64, 3,   0); return; }
    e -= 192;
    if (e < 4096)       { fold_one(e,          c1w, c1b, c1g, c1t, c1m, c1v, ws + W1T_OFF,  ws + B1_OFF,  64, 64,  0); return; }
    e -= 4096;
    if (e < 192)        { fold_one(e,          a0w, a0b, a0g, a0t, a0m, a0v, ws + A0XT_OFF, ws + BA0_OFF, 64, 67,  0); return; }
    e -= 192;
    if (e < 4096)       { fold_one(e,          a0w, a0b, a0g, a0t, a0m, a0v, ws + A0FT_OFF, nullptr,      64, 67,  3); return; }
    e -= 4096;
    if (e < 8192)       { fold_one(e,          a1w, a1b, a1g, a1t, a1m, a1v, ws + A1T_OFF,  ws + BA1_OFF, 128, 64, 0); return; }
    e -= 8192;
    if (e < 16384)      { fold_one(e,          a2w, a2b, a2g, a2t, a2m, a2v, ws + A2T_OFF,  ws + BA2_OFF, 128, 128,0); return; }
    e -= 16384;
    if (e < 65536)      { fold_one(e,          c2w, c2b, c2g, c2t, c2m, c2v, ws + C2T_OFF,  ws + BC2_OFF, 256, 256,0); return; }
    e -= 65536;
    if (e < 32768)      { fold_one(e,          c3w, c3b, c3g, c3t, c3m, c3v, ws + C3T_OFF,  ws + BC3_OFF, 128, 256,0); return; }
    e -= 32768;
    if (e < 768)        { fold_one(e,          c4w, c4b, nullptr, nullptr, nullptr, nullptr, ws + C4T_OFF, ws + BC4_OFF, 6, 128, 0); return; }
}

// ---------------------------------------------------------------------------
// Kernel 1: per-point MLP 3->64->64 (+ pts4 with exact sq, + q/c for a0 trick)
// block = 256 (4 waves = 4 points, lane = output channel)
// ---------------------------------------------------------------------------
__global__ __launch_bounds__(256) void point_mlp_kernel(const float* __restrict__ pts, float* __restrict__ ws)
{
    __shared__ float sh[4][64];
    __shared__ float sx[4][64];
    int lane = threadIdx.x & 63;
    int wv = threadIdx.x >> 6;
    int pid = blockIdx.x * 4 + wv;
    const float* p = pts + pid * 3;
    float x = p[0], y = p[1], z = p[2];
    if (lane == 0) {
        // exact reference order: sq = ((x*x + y*y) + z*z), no FMA contraction
        float sq = __fadd_rn(__fadd_rn(__fmul_rn(x, x), __fmul_rn(y, y)), __fmul_rn(z, z));
        ((float4*)(ws + PTS4_OFF))[pid] = make_float4(x, y, z, sq);
    }
    const float* W0T  = ws + W0T_OFF;
    const float* B0   = ws + B0_OFF;
    const float* W1T  = ws + W1T_OFF;
    const float* B1   = ws + B1_OFF;
    const float* A0XT = ws + A0XT_OFF;
    const float* A0FT = ws + A0FT_OFF;
    const float* BA0  = ws + BA0_OFF;

    float h0 = B0[lane];
    h0 = fmaf(x, W0T[lane], h0);
    h0 = fmaf(y, W0T[64 + lane], h0);
    h0 = fmaf(z, W0T[128 + lane], h0);
    h0 = fmaxf(h0, 0.0f);
    sh[wv][lane] = h0;
    __syncthreads();

    float acc = B1[lane];
    #pragma unroll 8
    for (int c = 0; c < 64; ++c) acc = fmaf(W1T[c * 64 + lane], sh[wv][c], acc);
    float x1 = fmaxf(acc, 0.0f);
    sx[wv][lane] = x1;

    float q = __fmul_rn(x, A0XT[lane]);
    q = fmaf(y, A0XT[64 + lane], q);
    q = fmaf(z, A0XT[128 + lane], q);
    ws[Q_OFF + pid * 64 + lane] = q;
    __syncthreads();

    float cacc = q + BA0[lane];
    #pragma unroll 8
    for (int c = 0; c < 64; ++c) cacc = fmaf(A0FT[c * 64 + lane], sx[wv][c], cacc);
    ws[C_OFF + pid * 64 + lane] = cacc;
}

// ---------------------------------------------------------------------------
// Kernel 2: exact kNN (k=16). block = 512 (8 waves x 64 rows); each wave scans
// a 512-candidate quarter. tau = 17th smallest of 32 group-minima (guaranteed
// >= true 16th smallest), filter-append, lexicographic extraction.
// ---------------------------------------------------------------------------
__device__ __forceinline__ float dist2_ref(float xn, float yn, float zn, float sqn, float4 pm)
{
    // reference: (sq_n + sq_m) - 2*dot;  dot via FMA chain (XLA/Eigen style)
    float dot = __fmul_rn(xn, pm.x);
    dot = __fmaf_rn(yn, pm.y, dot);
    dot = __fmaf_rn(zn, pm.z, dot);
    float s = __fadd_rn(sqn, pm.w);
    return __fsub_rn(s, __fmul_rn(2.0f, dot));
}

#define KNN_CAP 64
__global__ __launch_bounds__(512) void knn_kernel(float* __restrict__ ws)
{
    __shared__ float gmins[64 * 33];
    __shared__ float bufd[KNN_CAP * 64];
    __shared__ int   bufi[KNN_CAP * 64];
    __shared__ int   cnt[64];
    __shared__ float tau[64];

    const float4* pts4 = (const float4*)(ws + PTS4_OFF);
    int* IDX = (int*)(ws + IDX_OFF);

    int row = threadIdx.x & 63;
    int wv  = threadIdx.x >> 6;
    int r   = blockIdx.x * 64 + row;
    int base = (r >> 12) << 12;
    float4 pn = pts4[r];
    float xn = pn.x, yn = pn.y, zn = pn.z, sqn = pn.w;

    if (threadIdx.x < 64) cnt[threadIdx.x] = 0;

    // Pass A: minima of 4 contiguous groups of 128
    #pragma unroll
    for (int g = 0; g < 4; ++g) {
        float mn = INFINITY;
        int m0 = base + wv * 512 + g * 128;
        #pragma unroll 4
        for (int i = 0; i < 128; ++i) {
            float d = dist2_ref(xn, yn, zn, sqn, pts4[m0 + i]);
            mn = fminf(mn, d);
        }
        gmins[row * 33 + wv * 4 + g] = mn;
    }
    __syncthreads();

    // tau = 17th smallest of the 32 group minima (>= true 16th smallest dist)
    if (threadIdx.x < 64) {
        int rb = threadIdx.x * 33;
        float tv = 0.0f;
        for (int it = 0; it < 17; ++it) {
            float bm = INFINITY; int bj = 0;
            for (int j = 0; j < 32; ++j) {
                float vv = gmins[rb + j];
                if (vv < bm) { bm = vv; bj = j; }
            }
            gmins[rb + bj] = INFINITY;
            tv = bm;
        }
        tau[threadIdx.x] = tv;
    }
    __syncthreads();

    // Pass B: filter by tau, append (d, m) to per-row buffer
    {
        float tv = tau[row];
        int m0 = base + wv * 512;
        for (int i = 0; i < 512; ++i) {
            float d = dist2_ref(xn, yn, zn, sqn, pts4[m0 + i]);
            if (d <= tv) {
                int slot = atomicAdd(&cnt[row], 1);
                if (slot < KNN_CAP) {
                    bufd[slot * 64 + row] = d;
                    bufi[slot * 64 + row] = wv * 512 + i;
                }
            }
        }
    }
    __syncthreads();

    // Extraction: 16 lexicographic (d, idx) minima -> matches stable top_k
    if (threadIdx.x < 64) {
        int rw = threadIdx.x;
        int* out = IDX + (blockIdx.x * 64 + rw) * 16;
        int s = cnt[rw];
        if (s <= KNN_CAP) {
            for (int jj = 0; jj < 16; ++jj) {
                float bd = INFINITY; int bi = 0x7fffffff; int bs = 0;
                for (int t2 = 0; t2 < s; ++t2) {
                    float d = bufd[t2 * 64 + rw];
                    int   i = bufi[t2 * 64 + rw];
                    if (d < bd || (d == bd && i < bi)) { bd = d; bi = i; bs = t2; }
                }
                bufd[bs * 64 + rw] = INFINITY;
                out[jj] = bi;
            }
        } else {
            // overflow fallback (P ~ 1e-9): exact serial top-16
            float hd[16]; int hi[16];
            #pragma unroll
            for (int t2 = 0; t2 < 16; ++t2) { hd[t2] = INFINITY; hi[t2] = 0; }
            for (int mm = 0; mm < 4096; ++mm) {
                float d = dist2_ref(xn, yn, zn, sqn, pts4[base + mm]);
                if (d < hd[15]) {
                    float vd = d; int vi = mm;
                    #pragma unroll
                    for (int t2 = 0; t2 < 16; ++t2) {
                        bool sm = vd < hd[t2];
                        float td = hd[t2]; int ti = hi[t2];
                        if (sm) { hd[t2] = vd; hi[t2] = vi; vd = td; vi = ti; }
                    }
                }
            }
            for (int jj = 0; jj < 16; ++jj) out[jj] = hi[jj];
        }
    }
}

// ---------------------------------------------------------------------------
// Kernel 3: per-pair MLP a1 (64->128) + a2 (128->128) + max over k.
// block = 256, P=4 points -> M=64 rows. G1[r][c] = relu(C[m_r][c] - Q[p_r][c]).
// LDS: sX 32KB (G1t then swizzled H1t), sB 8KB (weight quarter stages).
// ---------------------------------------------------------------------------
__global__ __launch_bounds__(256) void nbr_mlp_kernel(float* __restrict__ ws)
{
    __shared__ __align__(16) float sX[128 * 64];  // 32KB
    __shared__ __align__(16) float sB[16 * 128];  // 8KB
    const int t  = threadIdx.x;
    const int tr = t >> 4;   // 0..15, rows tr*4
    const int tc = t & 15;   // 0..15, cols tc*8
    const int blk = blockIdx.x;
    const int b = blk >> 10;
    const int gpt0 = blk * 4;
    const int base = b << 12;

    const float* Cf = ws + C_OFF;
    const float* Qf = ws + Q_OFF;
    const int* IDX = (const int*)(ws + IDX_OFF);

    // stage G1t[c][r]
    {
        int r = t & 63;
        int cq = t >> 6;
        int gpt = gpt0 + (r >> 4);
        int m = IDX[gpt * 16 + (r & 15)];
        const float4* crow = (const float4*)(Cf + (size_t)(base + m) * 64);
        const float4* qrow = (const float4*)(Qf + (size_t)gpt * 64);
        #pragma unroll
        for (int u = 0; u < 4; ++u) {
            int f4 = cq * 4 + u;
            float4 cv = crow[f4];
            float4 qv = qrow[f4];
            int c = f4 * 4;
            sX[(c + 0) * 64 + r] = fmaxf(cv.x - qv.x, 0.0f);
            sX[(c + 1) * 64 + r] = fmaxf(cv.y - qv.y, 0.0f);
            sX[(c + 2) * 64 + r] = fmaxf(cv.z - qv.z, 0.0f);
            sX[(c + 3) * 64 + r] = fmaxf(cv.w - qv.w, 0.0f);
        }
    }

    float acc[4][8];
    #pragma unroll
    for (int i = 0; i < 4; ++i)
        #pragma unroll
        for (int j = 0; j < 8; ++j) acc[i][j] = 0.0f;

    // GEMM1: M64 K64 N128, 4 phases of 16 k
    const float* A1T = ws + A1T_OFF;
    for (int ph = 0; ph < 4; ++ph) {
        __syncthreads();
        {
            const float4* src = (const float4*)(A1T + ph * 2048);
            float4* dst = (float4*)sB;
            dst[t * 2 + 0] = src[t * 2 + 0];
            dst[t * 2 + 1] = src[t * 2 + 1];
        }
        __syncthreads();
        #pragma unroll
        for (int k2 = 0; k2 < 16; ++k2) {
            int k = ph * 16 + k2;
            float4 a  = *(const float4*)&sX[k * 64 + tr * 4];
            float4 b0 = *(const float4*)&sB[k2 * 128 + tc * 8];
            float4 b1 = *(const float4*)&sB[k2 * 128 + tc * 8 + 4];
            float av[4] = {a.x, a.y, a.z, a.w};
            float bv[8] = {b0.x, b0.y, b0.z, b0.w, b1.x, b1.y, b1.z, b1.w};
            #pragma unroll
            for (int i = 0; i < 4; ++i)
                #pragma unroll
                for (int j = 0; j < 8; ++j)
                    acc[i][j] = fmaf(av[i], bv[j], acc[i][j]);
        }
    }
    __syncthreads();

    // epilogue1: relu+bias, write H1t swizzled (2-way-free bank pattern)
    {
        const float* BA1 = ws + BA1_OFF;
        int mbase = (tr * 4 + 8 * (tc & 7)) & 63;
        #pragma unroll
        for (int j = 0; j < 8; ++j) {
            int col = tc * 8 + j;
            float bias = BA1[col];
            float4 hv;
            hv.x = fmaxf(acc[0][j] + bias, 0.0f);
            hv.y = fmaxf(acc[1][j] + bias, 0.0f);
            hv.z = fmaxf(acc[2][j] + bias, 0.0f);
            hv.w = fmaxf(acc[3][j] + bias, 0.0f);
            *(float4*)&sX[col * 64 + mbase] = hv;
        }
    }
    __syncthreads();

    #pragma unroll
    for (int i = 0; i < 4; ++i)
        #pragma unroll
        for (int j = 0; j < 8; ++j) acc[i][j] = 0.0f;

    // GEMM2: M64 K128 N128, 8 phases of 16 k
    const float* A2T = ws + A2T_OFF;
    for (int ph = 0; ph < 8; ++ph) {
        __syncthreads();
        {
            const float4* src = (const float4*)(A2T + ph * 2048);
            float4* dst = (float4*)sB;
            dst[t * 2 + 0] = src[t * 2 + 0];
            dst[t * 2 + 1] = src[t * 2 + 1];
        }
        __syncthreads();
        #pragma unroll
        for (int k2 = 0; k2 < 16; ++k2) {
            int k = ph * 16 + k2;
            int ashift = 8 * ((k >> 3) & 7);
            float4 a  = *(const float4*)&sX[k * 64 + ((tr * 4 + ashift) & 63)];
            float4 b0 = *(const float4*)&sB[k2 * 128 + tc * 8];
            float4 b1 = *(const float4*)&sB[k2 * 128 + tc * 8 + 4];
            float av[4] = {a.x, a.y, a.z, a.w};
            float bv[8] = {b0.x, b0.y, b0.z, b0.w, b1.x, b1.y, b1.z, b1.w};
            #pragma unroll
            for (int i = 0; i < 4; ++i)
                #pragma unroll
                for (int j = 0; j < 8; ++j)
                    acc[i][j] = fmaf(av[i], bv[j], acc[i][j]);
        }
    }
    __syncthreads();

    // epilogue2: relu+bias, max over k (per point) via LDS int atomicMax
    {
        const float* BA2 = ws + BA2_OFF;
        int* lmax = (int*)sB;
        lmax[t] = 0; lmax[t + 256] = 0;
        __syncthreads();
        int p = tr >> 2;
        #pragma unroll
        for (int j = 0; j < 8; ++j) {
            int col = tc * 8 + j;
            float bias = BA2[col];
            float v = fmaxf(fmaxf(acc[0][j] + bias, acc[1][j] + bias),
                            fmaxf(acc[2][j] + bias, acc[3][j] + bias));
            v = fmaxf(v, 0.0f);
            atomicMax(&lmax[p * 128 + col], __float_as_int(v));
        }
        __syncthreads();
        float* LOCAL = ws + LOCAL_OFF;
        #pragma unroll
        for (int u = 0; u < 2; ++u) {
            int e = t + u * 256;
            int pp = e >> 7, cc = e & 127;
            LOCAL[(size_t)(gpt0 + pp) * 128 + cc] = __int_as_float(lmax[e]);
        }
    }
}

// ---------------------------------------------------------------------------
// Kernel 4: global feature = max over N of local. grid (8, 32), block 128.
// ---------------------------------------------------------------------------
__global__ __launch_bounds__(128) void gf_kernel(float* __restrict__ ws)
{
    int b = blockIdx.x, sl = blockIdx.y;
    int c = threadIdx.x;
    const float* LOCAL = ws + LOCAL_OFF + (size_t)(b * 4096 + sl * 128) * 128;
    float m = 0.0f;
    #pragma unroll 4
    for (int i = 0; i < 128; ++i) m = fmaxf(m, LOCAL[i * 128 + c]);
    atomicMax((int*)(ws + GF_OFF) + b * 128 + c, __float_as_int(m));
}

// ---------------------------------------------------------------------------
// Kernel 5: head c2 (256->256) -> c3 (256->128) -> c4 (128->6).
// block 256, P=32 points. LDS: sF 32KB (featT / hT / h3T), sB 16KB stages.
// ---------------------------------------------------------------------------
__global__ __launch_bounds__(256) void head_kernel(float* __restrict__ ws, float* __restrict__ out)
{
    __shared__ __align__(16) float sF[256 * 32];  // 32KB
    __shared__ __align__(16) float sB[16 * 256];  // 16KB
    int t = threadIdx.x;
    int b = blockIdx.x >> 7;
    int gpt0 = blockIdx.x * 32;

    // stage featT[k][m]: k<128 local, k>=128 gf broadcast
    {
        int m = t >> 3;
        const float4* src = (const float4*)(ws + LOCAL_OFF + (size_t)(gpt0 + m) * 128);
        #pragma unroll
        for (int u = 0; u < 4; ++u) {
            int f4 = (t & 7) * 4 + u;
            float4 v = src[f4];
            int k = f4 * 4;
            sF[(k + 0) * 32 + m] = v.x;
            sF[(k + 1) * 32 + m] = v.y;
            sF[(k + 2) * 32 + m] = v.z;
            sF[(k + 3) * 32 + m] = v.w;
        }
        const float4* gsrc = (const float4*)(ws + GF_OFF + b * 128);
        #pragma unroll
        for (int u = 0; u < 4; ++u) {
            int f4 = (t & 7) * 4 + u;
            float4 v = gsrc[f4];
            int k = 128 + f4 * 4;
            sF[(k + 0) * 32 + m] = v.x;
            sF[(k + 1) * 32 + m] = v.y;
            sF[(k + 2) * 32 + m] = v.z;
            sF[(k + 3) * 32 + m] = v.w;
        }
    }

    // ---- c2: M32 K256 N256 ----
    int tr = t >> 5;   // 0..7, rows tr*4
    int tc = t & 31;   // cols tc*8
    float acc[4][8];
    #pragma unroll
    for (int i = 0; i < 4; ++i)
        #pragma unroll
        for (int j = 0; j < 8; ++j) acc[i][j] = 0.0f;

    const float* C2T = ws + C2T_OFF;
    for (int ph = 0; ph < 16; ++ph) {
        __syncthreads();
        {
            const float4* src = (const float4*)(C2T + ph * 4096);
            float4* dst = (float4*)sB;
            #pragma unroll
            for (int u = 0; u < 4; ++u) dst[t * 4 + u] = src[t * 4 + u];
        }
        __syncthreads();
        #pragma unroll
        for (int k2 = 0; k2 < 16; ++k2) {
            float4 a  = *(const float4*)&sF[(ph * 16 + k2) * 32 + tr * 4];
            float4 b0 = *(const float4*)&sB[k2 * 256 + tc * 8];
            float4 b1 = *(const float4*)&sB[k2 * 256 + tc * 8 + 4];
            float av[4] = {a.x, a.y, a.z, a.w};
            float bv[8] = {b0.x, b0.y, b0.z, b0.w, b1.x, b1.y, b1.z, b1.w};
            #pragma unroll
            for (int i = 0; i < 4; ++i)
                #pragma unroll
                for (int j = 0; j < 8; ++j)
                    acc[i][j] = fmaf(av[i], bv[j], acc[i][j]);
        }
    }
    __syncthreads();
    // epilogue c2 -> hT (swizzled)
    {
        const float* BC2 = ws + BC2_OFF;
        int mbase = (tr * 4 + 4 * (tc & 7)) & 31;
        #pragma unroll
        for (int j = 0; j < 8; ++j) {
            int col = tc * 8 + j;
            float bias = BC2[col];
            float4 hv;
            hv.x = fmaxf(acc[0][j] + bias, 0.0f);
            hv.y = fmaxf(acc[1][j] + bias, 0.0f);
            hv.z = fmaxf(acc[2][j] + bias, 0.0f);
            hv.w = fmaxf(acc[3][j] + bias, 0.0f);
            *(float4*)&sF[col * 32 + mbase] = hv;
        }
    }
    __syncthreads();

    // ---- c3: M32 K256 N128 ----
    int tr3 = t >> 5;
    int tc3 = t & 31;  // cols tc3*4
    float acc3[4][4];
    #pragma unroll
    for (int i = 0; i < 4; ++i)
        #pragma unroll
        for (int j = 0; j < 4; ++j) acc3[i][j] = 0.0f;

    const float* C3T = ws + C3T_OFF;
    for (int ph = 0; ph < 16; ++ph) {
        __syncthreads();
        {
            const float4* src = (const float4*)(C3T + ph * 2048);
            float4* dst = (float4*)sB;
            dst[t * 2 + 0] = src[t * 2 + 0];
            dst[t * 2 + 1] = src[t * 2 + 1];
        }
        __syncthreads();
        #pragma unroll
        for (int k2 = 0; k2 < 16; ++k2) {
            int k = ph * 16 + k2;
            int pos = (tr3 * 4 + 4 * ((k >> 3) & 7)) & 31;
            float4 a  = *(const float4*)&sF[k * 32 + pos];
            float4 b0 = *(const float4*)&sB[k2 * 128 + tc3 * 4];
            float av[4] = {a.x, a.y, a.z, a.w};
            float bv[4] = {b0.x, b0.y, b0.z, b0.w};
            #pragma unroll
            for (int i = 0; i < 4; ++i)
                #pragma unroll
                for (int j = 0; j < 4; ++j)
                    acc3[i][j] = fmaf(av[i], bv[j], acc3[i][j]);
        }
    }
    __syncthreads();
    // epilogue c3 -> h3T (swizzled)
    {
        const float* BC3 = ws + BC3_OFF;
        #pragma unroll
        for (int j = 0; j < 4; ++j) {
            int col = tc3 * 4 + j;
            int mbase = (tr3 * 4 + 4 * ((col >> 3) & 7)) & 31;
            float bias = BC3[col];
            float4 hv;
            hv.x = fmaxf(acc3[0][j] + bias, 0.0f);
            hv.y = fmaxf(acc3[1][j] + bias, 0.0f);
            hv.z = fmaxf(acc3[2][j] + bias, 0.0f);
            hv.w = fmaxf(acc3[3][j] + bias, 0.0f);
            *(float4*)&sF[col * 32 + mbase] = hv;
        }
    }
    __syncthreads();

    // ---- c4: 128 -> 6, no BN/relu ----
    if (t < 192) {
        const float* C4T = ws + C4T_OFF;
        const float* BC4 = ws + BC4_OFF;
        int m = t / 6, o = t % 6;
        float a = BC4[o];
        #pragma unroll 8
        for (int k = 0; k < 128; ++k) {
            int pos = (m + 4 * ((k >> 3) & 7)) & 31;
            a = fmaf(sF[k * 32 + pos], C4T[k * 6 + o], a);
        }
        out[(size_t)(gpt0 + m) * 6 + o] = a;
    }
}

// ---------------------------------------------------------------------------
extern "C" void kernel_launch(void* const* d_in, const int* in_sizes, int n_in,
                              void* d_out, int out_size, void* d_ws, size_t ws_size,
                              hipStream_t stream)
{
    const float* pts = (const float*)d_in[0];
    float* ws = (float*)d_ws;
    float* out = (float*)d_out;

    hipMemsetAsync(ws + GF_OFF, 0, 1024 * sizeof(float), stream);

    fold_kernel<<<517, 256, 0, stream>>>(
        (const float*)d_in[1],  (const float*)d_in[2],  (const float*)d_in[3],  (const float*)d_in[4],  (const float*)d_in[5],  (const float*)d_in[6],
        (const float*)d_in[7],  (const float*)d_in[8],  (const float*)d_in[9],  (const float*)d_in[10], (const float*)d_in[11], (const float*)d_in[12],
        (const float*)d_in[13], (const float*)d_in[14], (const float*)d_in[15], (const float*)d_in[16], (const float*)d_in[17], (const float*)d_in[18],
        (const float*)d_in[19], (const float*)d_in[20], (const float*)d_in[21], (const float*)d_in[22], (const float*)d_in[23], (const float*)d_in[24],
        (const float*)d_in[25], (const float*)d_in[26], (const float*)d_in[27], (const float*)d_in[28], (const float*)d_in[29], (const float*)d_in[30],
        (const float*)d_in[31], (const float*)d_in[32], (const float*)d_in[33], (const float*)d_in[34], (const float*)d_in[35], (const float*)d_in[36],
        (const float*)d_in[37], (const float*)d_in[38], (const float*)d_in[39], (const float*)d_in[40], (const float*)d_in[41], (const float*)d_in[42],
        (const float*)d_in[43], (const float*)d_in[44],
        ws);

    point_mlp_kernel<<<8192, 256, 0, stream>>>(pts, ws);
    knn_kernel<<<512, 512, 0, stream>>>(ws);
    nbr_mlp_kernel<<<8192, 256, 0, stream>>>(ws);
    gf_kernel<<<dim3(8, 32), 128, 0, stream>>>(ws);
    head_kernel<<<1024, 256, 0, stream>>>(ws, out);
}

// Round 2
// 644.943 us; speedup vs baseline: 1.3139x; 1.3139x over previous
//
#include <hip/hip_runtime.h>
#include <math.h>

// ============================================================================
// Round 2: nbr_mlp rewritten on fp16 MFMA (32x32x16), transposed formulation.
// Everything else kept from Round 1 (fp32, passing at 2.4e-4).
// ============================================================================

#define EPSBN 1e-5f

typedef _Float16 v8h  __attribute__((ext_vector_type(8)));
typedef _Float16 v4h  __attribute__((ext_vector_type(4)));
typedef float    v16f __attribute__((ext_vector_type(16)));

// ---- ws layout (float offsets) ----
#define W0T_OFF   0         // [3][64]
#define B0_OFF    192
#define W1T_OFF   256       // [64][64]
#define B1_OFF    4352
#define A0XT_OFF  4416      // [3][64]
#define A0FT_OFF  4608      // [64][64]
#define BA0_OFF   8704
#define A1T_OFF   8768      // fp16 image [128][64]h swizzled (8192 halfs)
#define BA1_OFF   16960
#define A2T_OFF   17088     // fp16 image [128][128]h swizzled (16384 halfs)
#define BA2_OFF   33472
#define C2T_OFF   33600     // [256][256]
#define BC2_OFF   99136
#define C3T_OFF   99392     // [256][128]
#define BC3_OFF   132160
#define C4T_OFF   132288    // [128][6]
#define BC4_OFF   133056
#define PTS4_OFF  133120    // [32768] float4 {x,y,z,sq}
#define Q_OFF     264192    // [32768][64]
#define C_OFF     2361344   // [32768][64]
#define IDX_OFF   4458496   // [32768][16] int (batch-local m)
#define LOCAL_OFF 4982784   // [32768][128]
#define GF_OFF    9177088   // [8][128]

// ---------------------------------------------------------------------------
// Kernel 0: fold BN into weights. a1/a2 stored as fp16 swizzled MFMA images;
// all other layers fp32 transposed (k-major) as in Round 1.
// ---------------------------------------------------------------------------
__device__ __forceinline__ void fold_one(int e, const float* w, const float* b,
    const float* g, const float* t, const float* m, const float* v,
    float* wt, float* bo, int O, int Cfull, int cbeg)
{
    int o = e % O, c = e / O;
    float s = 1.0f;
    if (g) s = g[o] * (1.0f / sqrtf(v[o] + EPSBN));
    wt[c * O + o] = w[o * Cfull + cbeg + c] * s;
    if (c == 0 && bo) {
        float bias = b[o];
        if (g) bias = (bias - m[o]) * s + t[o];
        bo[o] = bias;
    }
}

__global__ __launch_bounds__(256) void fold_kernel(
    const float* c0w, const float* c0b, const float* c0g, const float* c0t, const float* c0m, const float* c0v,
    const float* c1w, const float* c1b, const float* c1g, const float* c1t, const float* c1m, const float* c1v,
    const float* a0w, const float* a0b, const float* a0g, const float* a0t, const float* a0m, const float* a0v,
    const float* a1w, const float* a1b, const float* a1g, const float* a1t, const float* a1m, const float* a1v,
    const float* a2w, const float* a2b, const float* a2g, const float* a2t, const float* a2m, const float* a2v,
    const float* c2w, const float* c2b, const float* c2g, const float* c2t, const float* c2m, const float* c2v,
    const float* c3w, const float* c3b, const float* c3g, const float* c3t, const float* c3m, const float* c3v,
    const float* c4w, const float* c4b,
    float* ws)
{
    int e = blockIdx.x * 256 + threadIdx.x;
    if (e < 192)        { fold_one(e,          c0w, c0b, c0g, c0t, c0m, c0v, ws + W0T_OFF,  ws + B0_OFF,  64, 3,   0); return; }
    e -= 192;
    if (e < 4096)       { fold_one(e,          c1w, c1b, c1g, c1t, c1m, c1v, ws + W1T_OFF,  ws + B1_OFF,  64, 64,  0); return; }
    e -= 4096;
    if (e < 192)        { fold_one(e,          a0w, a0b, a0g, a0t, a0m, a0v, ws + A0XT_OFF, ws + BA0_OFF, 64, 67,  0); return; }
    e -= 192;
    if (e < 4096)       { fold_one(e,          a0w, a0b, a0g, a0t, a0m, a0v, ws + A0FT_OFF, nullptr,      64, 67,  3); return; }
    e -= 4096;
    if (e < 8192) {
        // a1 fp16 swizzled image: img[o][ ((c>>3)^(o&7))*8 + (c&7) ] = w*s
        int o = e & 127, c = e >> 7;
        float s = a1g[o] * (1.0f / sqrtf(a1v[o] + EPSBN));
        float val = a1w[o * 64 + c] * s;
        ((_Float16*)(ws + A1T_OFF))[o * 64 + (((c >> 3) ^ (o & 7)) * 8) + (c & 7)] = (_Float16)val;
        if (c == 0) ws[BA1_OFF + o] = (a1b[o] - a1m[o]) * s + a1t[o];
        return;
    }
    e -= 8192;
    if (e < 16384) {
        int o = e & 127, c = e >> 7;
        float s = a2g[o] * (1.0f / sqrtf(a2v[o] + EPSBN));
        float val = a2w[o * 128 + c] * s;
        ((_Float16*)(ws + A2T_OFF))[o * 128 + (((c >> 3) ^ (o & 7)) * 8) + (c & 7)] = (_Float16)val;
        if (c == 0) ws[BA2_OFF + o] = (a2b[o] - a2m[o]) * s + a2t[o];
        return;
    }
    e -= 16384;
    if (e < 65536)      { fold_one(e,          c2w, c2b, c2g, c2t, c2m, c2v, ws + C2T_OFF,  ws + BC2_OFF, 256, 256,0); return; }
    e -= 65536;
    if (e < 32768)      { fold_one(e,          c3w, c3b, c3g, c3t, c3m, c3v, ws + C3T_OFF,  ws + BC3_OFF, 128, 256,0); return; }
    e -= 32768;
    if (e < 768)        { fold_one(e,          c4w, c4b, nullptr, nullptr, nullptr, nullptr, ws + C4T_OFF, ws + BC4_OFF, 6, 128, 0); return; }
}

// ---------------------------------------------------------------------------
// Kernel 1: per-point MLP 3->64->64 (+ pts4 with exact sq, + q/c for a0 trick)
// ---------------------------------------------------------------------------
__global__ __launch_bounds__(256) void point_mlp_kernel(const float* __restrict__ pts, float* __restrict__ ws)
{
    __shared__ float sh[4][64];
    __shared__ float sx[4][64];
    int lane = threadIdx.x & 63;
    int wv = threadIdx.x >> 6;
    int pid = blockIdx.x * 4 + wv;
    const float* p = pts + pid * 3;
    float x = p[0], y = p[1], z = p[2];
    if (lane == 0) {
        float sq = __fadd_rn(__fadd_rn(__fmul_rn(x, x), __fmul_rn(y, y)), __fmul_rn(z, z));
        ((float4*)(ws + PTS4_OFF))[pid] = make_float4(x, y, z, sq);
    }
    const float* W0T  = ws + W0T_OFF;
    const float* B0   = ws + B0_OFF;
    const float* W1T  = ws + W1T_OFF;
    const float* B1   = ws + B1_OFF;
    const float* A0XT = ws + A0XT_OFF;
    const float* A0FT = ws + A0FT_OFF;
    const float* BA0  = ws + BA0_OFF;

    float h0 = B0[lane];
    h0 = fmaf(x, W0T[lane], h0);
    h0 = fmaf(y, W0T[64 + lane], h0);
    h0 = fmaf(z, W0T[128 + lane], h0);
    h0 = fmaxf(h0, 0.0f);
    sh[wv][lane] = h0;
    __syncthreads();

    float acc = B1[lane];
    #pragma unroll 8
    for (int c = 0; c < 64; ++c) acc = fmaf(W1T[c * 64 + lane], sh[wv][c], acc);
    float x1 = fmaxf(acc, 0.0f);
    sx[wv][lane] = x1;

    float q = __fmul_rn(x, A0XT[lane]);
    q = fmaf(y, A0XT[64 + lane], q);
    q = fmaf(z, A0XT[128 + lane], q);
    ws[Q_OFF + pid * 64 + lane] = q;
    __syncthreads();

    float cacc = q + BA0[lane];
    #pragma unroll 8
    for (int c = 0; c < 64; ++c) cacc = fmaf(A0FT[c * 64 + lane], sx[wv][c], cacc);
    ws[C_OFF + pid * 64 + lane] = cacc;
}

// ---------------------------------------------------------------------------
// Kernel 2: exact kNN (k=16) — unchanged from Round 1 (verified bit-exact).
// ---------------------------------------------------------------------------
__device__ __forceinline__ float dist2_ref(float xn, float yn, float zn, float sqn, float4 pm)
{
    float dot = __fmul_rn(xn, pm.x);
    dot = __fmaf_rn(yn, pm.y, dot);
    dot = __fmaf_rn(zn, pm.z, dot);
    float s = __fadd_rn(sqn, pm.w);
    return __fsub_rn(s, __fmul_rn(2.0f, dot));
}

#define KNN_CAP 64
__global__ __launch_bounds__(512) void knn_kernel(float* __restrict__ ws)
{
    __shared__ float gmins[64 * 33];
    __shared__ float bufd[KNN_CAP * 64];
    __shared__ int   bufi[KNN_CAP * 64];
    __shared__ int   cnt[64];
    __shared__ float tau[64];

    const float4* pts4 = (const float4*)(ws + PTS4_OFF);
    int* IDX = (int*)(ws + IDX_OFF);

    int row = threadIdx.x & 63;
    int wv  = threadIdx.x >> 6;
    int r   = blockIdx.x * 64 + row;
    int base = (r >> 12) << 12;
    float4 pn = pts4[r];
    float xn = pn.x, yn = pn.y, zn = pn.z, sqn = pn.w;

    if (threadIdx.x < 64) cnt[threadIdx.x] = 0;

    #pragma unroll
    for (int g = 0; g < 4; ++g) {
        float mn = INFINITY;
        int m0 = base + wv * 512 + g * 128;
        #pragma unroll 4
        for (int i = 0; i < 128; ++i) {
            float d = dist2_ref(xn, yn, zn, sqn, pts4[m0 + i]);
            mn = fminf(mn, d);
        }
        gmins[row * 33 + wv * 4 + g] = mn;
    }
    __syncthreads();

    if (threadIdx.x < 64) {
        int rb = threadIdx.x * 33;
        float tv = 0.0f;
        for (int it = 0; it < 17; ++it) {
            float bm = INFINITY; int bj = 0;
            for (int j = 0; j < 32; ++j) {
                float vv = gmins[rb + j];
                if (vv < bm) { bm = vv; bj = j; }
            }
            gmins[rb + bj] = INFINITY;
            tv = bm;
        }
        tau[threadIdx.x] = tv;
    }
    __syncthreads();

    {
        float tv = tau[row];
        int m0 = base + wv * 512;
        for (int i = 0; i < 512; ++i) {
            float d = dist2_ref(xn, yn, zn, sqn, pts4[m0 + i]);
            if (d <= tv) {
                int slot = atomicAdd(&cnt[row], 1);
                if (slot < KNN_CAP) {
                    bufd[slot * 64 + row] = d;
                    bufi[slot * 64 + row] = wv * 512 + i;
                }
            }
        }
    }
    __syncthreads();

    if (threadIdx.x < 64) {
        int rw = threadIdx.x;
        int* out = IDX + (blockIdx.x * 64 + rw) * 16;
        int s = cnt[rw];
        if (s <= KNN_CAP) {
            for (int jj = 0; jj < 16; ++jj) {
                float bd = INFINITY; int bi = 0x7fffffff; int bs = 0;
                for (int t2 = 0; t2 < s; ++t2) {
                    float d = bufd[t2 * 64 + rw];
                    int   i = bufi[t2 * 64 + rw];
                    if (d < bd || (d == bd && i < bi)) { bd = d; bi = i; bs = t2; }
                }
                bufd[bs * 64 + rw] = INFINITY;
                out[jj] = bi;
            }
        } else {
            float hd[16]; int hi[16];
            #pragma unroll
            for (int t2 = 0; t2 < 16; ++t2) { hd[t2] = INFINITY; hi[t2] = 0; }
            for (int mm = 0; mm < 4096; ++mm) {
                float d = dist2_ref(xn, yn, zn, sqn, pts4[base + mm]);
                if (d < hd[15]) {
                    float vd = d; int vi = mm;
                    #pragma unroll
                    for (int t2 = 0; t2 < 16; ++t2) {
                        bool sm = vd < hd[t2];
                        float td = hd[t2]; int ti = hi[t2];
                        if (sm) { hd[t2] = vd; hi[t2] = vi; vd = td; vi = ti; }
                    }
                }
            }
            for (int jj = 0; jj < 16; ++jj) out[jj] = hi[jj];
        }
    }
}

// ---------------------------------------------------------------------------
// Kernel 3 (NEW): a1+a2 via fp16 MFMA 32x32x16, transposed form.
//   H1^T[o][r] = sum_c W1[o][c] * G1[r][c]   (A = W1 [o][c], B = G1 [r][c])
//   H2^T[o][r] = sum_c W2[o][c] * H1[r][c]
// Both operands are row-major-contiguous 8-half fragments; XOR-(row&7)
// swizzle on 8-half groups gives the conflict-free bank floor.
// Block = 256 threads (4 waves), 64 rows = 4 points x 16 neighbors.
// Wave w owns the o-strip [w*32, w*32+32); loops r-tiles rt=0,1.
// Maxpool over 16 neighbors = 4 shfl_xor levels on the C-tile (col = r).
// ---------------------------------------------------------------------------
__global__ __launch_bounds__(256) void nbr_mlp_mfma_kernel(float* __restrict__ ws)
{
    __shared__ __align__(16) _Float16 sH1[64 * 128];   // 16KB  [r][c] swz
    __shared__ __align__(16) _Float16 sWG[16384];      // 32KB union
    _Float16* sW1 = sWG;            // phase 1: [128][64]h swz
    _Float16* sG1 = sWG + 8192;     // phase 1: [64][64]h swz
    _Float16* sW2 = sWG;            // phase 2: [128][128]h swz

    const int t   = threadIdx.x;
    const int l   = t & 63;
    const int w   = t >> 6;       // wave id = o-tile
    const int ln  = l & 31;
    const int hi  = l >> 5;       // 0/1
    const int blk = blockIdx.x;
    const int gpt0 = blk * 4;
    const int base = (blk >> 10) << 12;

    const float* Cf = ws + C_OFF;
    const float* Qf = ws + Q_OFF;
    const int* IDX = (const int*)(ws + IDX_OFF);
    const float4* w1img = (const float4*)(ws + A1T_OFF);  // 1024 float4
    const float4* w2img = (const float4*)(ws + A2T_OFF);  // 2048 float4

    // prefetch W2 into registers (issued early, consumed after a1)
    float4 w2r[8];
    #pragma unroll
    for (int u = 0; u < 8; ++u) w2r[u] = w2img[t + 256 * u];

    // stage W1 (flat 16KB copy; image is pre-swizzled by fold_kernel)
    {
        float4* d = (float4*)sW1;
        #pragma unroll
        for (int u = 0; u < 4; ++u) d[t + 256 * u] = w1img[t + 256 * u];
    }
    // stage G1[r][c] = relu(C[m_r][c] - Q[p_r][c]) as fp16, swizzled groups
    {
        int r = t >> 2, cs = t & 3;           // 16 channels per thread
        int gpt = gpt0 + (r >> 4);
        int m = IDX[gpt * 16 + (r & 15)];
        const float4* crow = (const float4*)(Cf + (size_t)(base + m) * 64) + cs * 4;
        const float4* qrow = (const float4*)(Qf + (size_t)gpt * 64) + cs * 4;
        v8h h0, h1;
        #pragma unroll
        for (int u = 0; u < 2; ++u) {
            float4 cv = crow[u], qv = qrow[u];
            h0[u * 4 + 0] = (_Float16)fmaxf(cv.x - qv.x, 0.0f);
            h0[u * 4 + 1] = (_Float16)fmaxf(cv.y - qv.y, 0.0f);
            h0[u * 4 + 2] = (_Float16)fmaxf(cv.z - qv.z, 0.0f);
            h0[u * 4 + 3] = (_Float16)fmaxf(cv.w - qv.w, 0.0f);
        }
        #pragma unroll
        for (int u = 0; u < 2; ++u) {
            float4 cv = crow[2 + u], qv = qrow[2 + u];
            h1[u * 4 + 0] = (_Float16)fmaxf(cv.x - qv.x, 0.0f);
            h1[u * 4 + 1] = (_Float16)fmaxf(cv.y - qv.y, 0.0f);
            h1[u * 4 + 2] = (_Float16)fmaxf(cv.z - qv.z, 0.0f);
            h1[u * 4 + 3] = (_Float16)fmaxf(cv.w - qv.w, 0.0f);
        }
        int rs = r & 7;
        *(v8h*)&sG1[r * 64 + ((cs * 2    ) ^ rs) * 8] = h0;
        *(v8h*)&sG1[r * 64 + ((cs * 2 + 1) ^ rs) * 8] = h1;
    }
    // per-wave bias vectors (o = w*32 + (i&3) + 8*(i>>2) + 4*hi)
    float bias1[16], bias2[16];
    #pragma unroll
    for (int i = 0; i < 16; ++i) {
        int ob = w * 32 + (i & 3) + 8 * (i >> 2) + 4 * hi;
        bias1[i] = ws[BA1_OFF + ob];
        bias2[i] = ws[BA2_OFF + ob];
    }
    __syncthreads();

    // ---- a1 ----
    v8h fa[4];
    {
        int o = w * 32 + ln, os = o & 7;
        #pragma unroll
        for (int kf = 0; kf < 4; ++kf)
            fa[kf] = *(const v8h*)&sW1[o * 64 + ((kf * 2 + hi) ^ os) * 8];
    }
    #pragma unroll
    for (int rt = 0; rt < 2; ++rt) {
        int r = rt * 32 + ln, rs = r & 7;
        v16f acc;
        #pragma unroll
        for (int i = 0; i < 16; ++i) acc[i] = 0.0f;
        #pragma unroll
        for (int kf = 0; kf < 4; ++kf) {
            v8h fb = *(const v8h*)&sG1[r * 64 + ((kf * 2 + hi) ^ rs) * 8];
            acc = __builtin_amdgcn_mfma_f32_32x32x16_f16(fa[kf], fb, acc, 0, 0, 0);
        }
        // epilogue: relu(acc + bias1) -> sH1[r][c], 4-half packed writes
        #pragma unroll
        for (int q = 0; q < 4; ++q) {
            v4h hv;
            #pragma unroll
            for (int j = 0; j < 4; ++j)
                hv[j] = (_Float16)fmaxf(acc[q * 4 + j] + bias1[q * 4 + j], 0.0f);
            int g = w * 4 + q;
            *(v4h*)&sH1[r * 128 + ((g ^ rs) * 8) + 4 * hi] = hv;
        }
    }
    __syncthreads();
    // stage W2 from regs
    {
        float4* d = (float4*)sW2;
        #pragma unroll
        for (int u = 0; u < 8; ++u) d[t + 256 * u] = w2r[u];
    }
    __syncthreads();

    // ---- a2 ----
    v8h fa2[8];
    {
        int o = w * 32 + ln, os = o & 7;
        #pragma unroll
        for (int kf = 0; kf < 8; ++kf)
            fa2[kf] = *(const v8h*)&sW2[o * 128 + ((kf * 2 + hi) ^ os) * 8];
    }
    float* LOCAL = ws + LOCAL_OFF;
    #pragma unroll
    for (int rt = 0; rt < 2; ++rt) {
        int r = rt * 32 + ln, rs = r & 7;
        v16f acc;
        #pragma unroll
        for (int i = 0; i < 16; ++i) acc[i] = 0.0f;
        #pragma unroll
        for (int kf = 0; kf < 8; ++kf) {
            v8h fb = *(const v8h*)&sH1[r * 128 + ((kf * 2 + hi) ^ rs) * 8];
            acc = __builtin_amdgcn_mfma_f32_32x32x16_f16(fa2[kf], fb, acc, 0, 0, 0);
        }
        // maxpool over 16 neighbors: reduce across lane bits 0-3 (col = r)
        #pragma unroll
        for (int i = 0; i < 16; ++i) {
            float v = acc[i];
            v = fmaxf(v, __shfl_xor(v, 1));
            v = fmaxf(v, __shfl_xor(v, 2));
            v = fmaxf(v, __shfl_xor(v, 4));
            v = fmaxf(v, __shfl_xor(v, 8));
            acc[i] = v;
        }
        if ((l & 15) == 0) {
            int p = gpt0 + rt * 2 + ((l >> 4) & 1);
            #pragma unroll
            for (int q = 0; q < 4; ++q) {
                float4 o4;
                o4.x = fmaxf(acc[q * 4 + 0] + bias2[q * 4 + 0], 0.0f);
                o4.y = fmaxf(acc[q * 4 + 1] + bias2[q * 4 + 1], 0.0f);
                o4.z = fmaxf(acc[q * 4 + 2] + bias2[q * 4 + 2], 0.0f);
                o4.w = fmaxf(acc[q * 4 + 3] + bias2[q * 4 + 3], 0.0f);
                int ob = w * 32 + 8 * q + 4 * hi;
                *(float4*)&LOCAL[(size_t)p * 128 + ob] = o4;
            }
        }
    }
}

// ---------------------------------------------------------------------------
// Kernel 4: global feature = max over N of local.
// ---------------------------------------------------------------------------
__global__ __launch_bounds__(128) void gf_kernel(float* __restrict__ ws)
{
    int b = blockIdx.x, sl = blockIdx.y;
    int c = threadIdx.x;
    const float* LOCAL = ws + LOCAL_OFF + (size_t)(b * 4096 + sl * 128) * 128;
    float m = 0.0f;
    #pragma unroll 4
    for (int i = 0; i < 128; ++i) m = fmaxf(m, LOCAL[i * 128 + c]);
    atomicMax((int*)(ws + GF_OFF) + b * 128 + c, __float_as_int(m));
}

// ---------------------------------------------------------------------------
// Kernel 5: head c2 -> c3 -> c4 (unchanged fp32).
// ---------------------------------------------------------------------------
__global__ __launch_bounds__(256) void head_kernel(float* __restrict__ ws, float* __restrict__ out)
{
    __shared__ __align__(16) float sF[256 * 32];
    __shared__ __align__(16) float sB[16 * 256];
    int t = threadIdx.x;
    int b = blockIdx.x >> 7;
    int gpt0 = blockIdx.x * 32;

    {
        int m = t >> 3;
        const float4* src = (const float4*)(ws + LOCAL_OFF + (size_t)(gpt0 + m) * 128);
        #pragma unroll
        for (int u = 0; u < 4; ++u) {
            int f4 = (t & 7) * 4 + u;
            float4 v = src[f4];
            int k = f4 * 4;
            sF[(k + 0) * 32 + m] = v.x;
            sF[(k + 1) * 32 + m] = v.y;
            sF[(k + 2) * 32 + m] = v.z;
            sF[(k + 3) * 32 + m] = v.w;
        }
        const float4* gsrc = (const float4*)(ws + GF_OFF + b * 128);
        #pragma unroll
        for (int u = 0; u < 4; ++u) {
            int f4 = (t & 7) * 4 + u;
            float4 v = gsrc[f4];
            int k = 128 + f4 * 4;
            sF[(k + 0) * 32 + m] = v.x;
            sF[(k + 1) * 32 + m] = v.y;
            sF[(k + 2) * 32 + m] = v.z;
            sF[(k + 3) * 32 + m] = v.w;
        }
    }

    int tr = t >> 5;
    int tc = t & 31;
    float acc[4][8];
    #pragma unroll
    for (int i = 0; i < 4; ++i)
        #pragma unroll
        for (int j = 0; j < 8; ++j) acc[i][j] = 0.0f;

    const float* C2T = ws + C2T_OFF;
    for (int ph = 0; ph < 16; ++ph) {
        __syncthreads();
        {
            const float4* src = (const float4*)(C2T + ph * 4096);
            float4* dst = (float4*)sB;
            #pragma unroll
            for (int u = 0; u < 4; ++u) dst[t * 4 + u] = src[t * 4 + u];
        }
        __syncthreads();
        #pragma unroll
        for (int k2 = 0; k2 < 16; ++k2) {
            float4 a  = *(const float4*)&sF[(ph * 16 + k2) * 32 + tr * 4];
            float4 b0 = *(const float4*)&sB[k2 * 256 + tc * 8];
            float4 b1 = *(const float4*)&sB[k2 * 256 + tc * 8 + 4];
            float av[4] = {a.x, a.y, a.z, a.w};
            float bv[8] = {b0.x, b0.y, b0.z, b0.w, b1.x, b1.y, b1.z, b1.w};
            #pragma unroll
            for (int i = 0; i < 4; ++i)
                #pragma unroll
                for (int j = 0; j < 8; ++j)
                    acc[i][j] = fmaf(av[i], bv[j], acc[i][j]);
        }
    }
    __syncthreads();
    {
        const float* BC2 = ws + BC2_OFF;
        int mbase = (tr * 4 + 4 * (tc & 7)) & 31;
        #pragma unroll
        for (int j = 0; j < 8; ++j) {
            int col = tc * 8 + j;
            float bias = BC2[col];
            float4 hv;
            hv.x = fmaxf(acc[0][j] + bias, 0.0f);
            hv.y = fmaxf(acc[1][j] + bias, 0.0f);
            hv.z = fmaxf(acc[2][j] + bias, 0.0f);
            hv.w = fmaxf(acc[3][j] + bias, 0.0f);
            *(float4*)&sF[col * 32 + mbase] = hv;
        }
    }
    __syncthreads();

    int tr3 = t >> 5;
    int tc3 = t & 31;
    float acc3[4][4];
    #pragma unroll
    for (int i = 0; i < 4; ++i)
        #pragma unroll
        for (int j = 0; j < 4; ++j) acc3[i][j] = 0.0f;

    const float* C3T = ws + C3T_OFF;
    for (int ph = 0; ph < 16; ++ph) {
        __syncthreads();
        {
            const float4* src = (const float4*)(C3T + ph * 2048);
            float4* dst = (float4*)sB;
            dst[t * 2 + 0] = src[t * 2 + 0];
            dst[t * 2 + 1] = src[t * 2 + 1];
        }
        __syncthreads();
        #pragma unroll
        for (int k2 = 0; k2 < 16; ++k2) {
            int k = ph * 16 + k2;
            int pos = (tr3 * 4 + 4 * ((k >> 3) & 7)) & 31;
            float4 a  = *(const float4*)&sF[k * 32 + pos];
            float4 b0 = *(const float4*)&sB[k2 * 128 + tc3 * 4];
            float av[4] = {a.x, a.y, a.z, a.w};
            float bv[4] = {b0.x, b0.y, b0.z, b0.w};
            #pragma unroll
            for (int i = 0; i < 4; ++i)
                #pragma unroll
                for (int j = 0; j < 4; ++j)
                    acc3[i][j] = fmaf(av[i], bv[j], acc3[i][j]);
        }
    }
    __syncthreads();
    {
        const float* BC3 = ws + BC3_OFF;
        #pragma unroll
        for (int j = 0; j < 4; ++j) {
            int col = tc3 * 4 + j;
            int mbase = (tr3 * 4 + 4 * ((col >> 3) & 7)) & 31;
            float bias = BC3[col];
            float4 hv;
            hv.x = fmaxf(acc3[0][j] + bias, 0.0f);
            hv.y = fmaxf(acc3[1][j] + bias, 0.0f);
            hv.z = fmaxf(acc3[2][j] + bias, 0.0f);
            hv.w = fmaxf(acc3[3][j] + bias, 0.0f);
            *(float4*)&sF[col * 32 + mbase] = hv;
        }
    }
    __syncthreads();

    if (t < 192) {
        const float* C4T = ws + C4T_OFF;
        const float* BC4 = ws + BC4_OFF;
        int m = t / 6, o = t % 6;
        float a = BC4[o];
        #pragma unroll 8
        for (int k = 0; k < 128; ++k) {
            int pos = (m + 4 * ((k >> 3) & 7)) & 31;
            a = fmaf(sF[k * 32 + pos], C4T[k * 6 + o], a);
        }
        out[(size_t)(gpt0 + m) * 6 + o] = a;
    }
}

// ---------------------------------------------------------------------------
extern "C" void kernel_launch(void* const* d_in, const int* in_sizes, int n_in,
                              void* d_out, int out_size, void* d_ws, size_t ws_size,
                              hipStream_t stream)
{
    const float* pts = (const float*)d_in[0];
    float* ws = (float*)d_ws;
    float* out = (float*)d_out;

    hipMemsetAsync(ws + GF_OFF, 0, 1024 * sizeof(float), stream);

    fold_kernel<<<517, 256, 0, stream>>>(
        (const float*)d_in[1],  (const float*)d_in[2],  (const float*)d_in[3],  (const float*)d_in[4],  (const float*)d_in[5],  (const float*)d_in[6],
        (const float*)d_in[7],  (const float*)d_in[8],  (const float*)d_in[9],  (const float*)d_in[10], (const float*)d_in[11], (const float*)d_in[12],
        (const float*)d_in[13], (const float*)d_in[14], (const float*)d_in[15], (const float*)d_in[16], (const float*)d_in[17], (const float*)d_in[18],
        (const float*)d_in[19], (const float*)d_in[20], (const float*)d_in[21], (const float*)d_in[22], (const float*)d_in[23], (const float*)d_in[24],
        (const float*)d_in[25], (const float*)d_in[26], (const float*)d_in[27], (const float*)d_in[28], (const float*)d_in[29], (const float*)d_in[30],
        (const float*)d_in[31], (const float*)d_in[32], (const float*)d_in[33], (const float*)d_in[34], (const float*)d_in[35], (const float*)d_in[36],
        (const float*)d_in[37], (const float*)d_in[38], (const float*)d_in[39], (const float*)d_in[40], (const float*)d_in[41], (const float*)d_in[42],
        (const float*)d_in[43], (const float*)d_in[44],
        ws);

    point_mlp_kernel<<<8192, 256, 0, stream>>>(pts, ws);
    knn_kernel<<<512, 512, 0, stream>>>(ws);
    nbr_mlp_mfma_kernel<<<8192, 256, 0, stream>>>(ws);
    gf_kernel<<<dim3(8, 32), 128, 0, stream>>>(ws);
    head_kernel<<<1024, 256, 0, stream>>>(ws, out);
}

// Round 3
// 565.340 us; speedup vs baseline: 1.4989x; 1.1408x over previous
//
#include <hip/hip_runtime.h>
#include <math.h>

// ============================================================================
// Round 3: (1) knn with full-batch LDS candidate staging (kills L2-latency
// stalls; pts working set 64KB > 32KB L1). (2) head c2/c3 on fp16 MFMA with
// fragment-linear weight images streamed from global; c3 output stays fp32.
// ============================================================================

#define EPSBN 1e-5f

typedef _Float16 v8h  __attribute__((ext_vector_type(8)));
typedef _Float16 v4h  __attribute__((ext_vector_type(4)));
typedef float    v16f __attribute__((ext_vector_type(16)));

// ---- ws layout (float offsets) ----
#define W0T_OFF   0         // [3][64]
#define B0_OFF    192
#define W1T_OFF   256       // [64][64]
#define B1_OFF    4352
#define A0XT_OFF  4416      // [3][64]
#define A0FT_OFF  4608      // [64][64]
#define BA0_OFF   8704
#define A1T_OFF   8768      // fp16 image [128][64]h swizzled (8192 halfs)
#define BA1_OFF   16960
#define A2T_OFF   17088     // fp16 image [128][128]h swizzled (16384 halfs)
#define BA2_OFF   33472
#define C2T_OFF   33600     // fp16 frag-linear c2 image: 8192 float4 (65536 h)
#define C3H_OFF   66368     // fp16 frag-linear c3 image: 4096 float4 (32768 h)
#define BC2_OFF   99136
#define BC3_OFF   132160
#define C4T_OFF   132288    // [128][6] fp32
#define BC4_OFF   133056
#define PTS4_OFF  133120    // [32768] float4 {x,y,z,sq}
#define Q_OFF     264192    // [32768][64]
#define C_OFF     2361344   // [32768][64]
#define IDX_OFF   4458496   // [32768][16] int (batch-local m)
#define LOCAL_OFF 4982784   // [32768][128]
#define GF_OFF    9177088   // [8][128]

// ---------------------------------------------------------------------------
// Kernel 0: fold BN into weights.
// ---------------------------------------------------------------------------
__device__ __forceinline__ void fold_one(int e, const float* w, const float* b,
    const float* g, const float* t, const float* m, const float* v,
    float* wt, float* bo, int O, int Cfull, int cbeg)
{
    int o = e % O, c = e / O;
    float s = 1.0f;
    if (g) s = g[o] * (1.0f / sqrtf(v[o] + EPSBN));
    wt[c * O + o] = w[o * Cfull + cbeg + c] * s;
    if (c == 0 && bo) {
        float bias = b[o];
        if (g) bias = (bias - m[o]) * s + t[o];
        bo[o] = bias;
    }
}

__global__ __launch_bounds__(256) void fold_kernel(
    const float* c0w, const float* c0b, const float* c0g, const float* c0t, const float* c0m, const float* c0v,
    const float* c1w, const float* c1b, const float* c1g, const float* c1t, const float* c1m, const float* c1v,
    const float* a0w, const float* a0b, const float* a0g, const float* a0t, const float* a0m, const float* a0v,
    const float* a1w, const float* a1b, const float* a1g, const float* a1t, const float* a1m, const float* a1v,
    const float* a2w, const float* a2b, const float* a2g, const float* a2t, const float* a2m, const float* a2v,
    const float* c2w, const float* c2b, const float* c2g, const float* c2t, const float* c2m, const float* c2v,
    const float* c3w, const float* c3b, const float* c3g, const float* c3t, const float* c3m, const float* c3v,
    const float* c4w, const float* c4b,
    float* ws)
{
    int e = blockIdx.x * 256 + threadIdx.x;
    if (e < 192)        { fold_one(e,          c0w, c0b, c0g, c0t, c0m, c0v, ws + W0T_OFF,  ws + B0_OFF,  64, 3,   0); return; }
    e -= 192;
    if (e < 4096)       { fold_one(e,          c1w, c1b, c1g, c1t, c1m, c1v, ws + W1T_OFF,  ws + B1_OFF,  64, 64,  0); return; }
    e -= 4096;
    if (e < 192)        { fold_one(e,          a0w, a0b, a0g, a0t, a0m, a0v, ws + A0XT_OFF, ws + BA0_OFF, 64, 67,  0); return; }
    e -= 192;
    if (e < 4096)       { fold_one(e,          a0w, a0b, a0g, a0t, a0m, a0v, ws + A0FT_OFF, nullptr,      64, 67,  3); return; }
    e -= 4096;
    if (e < 8192) {
        int o = e & 127, c = e >> 7;
        float s = a1g[o] * (1.0f / sqrtf(a1v[o] + EPSBN));
        float val = a1w[o * 64 + c] * s;
        ((_Float16*)(ws + A1T_OFF))[o * 64 + (((c >> 3) ^ (o & 7)) * 8) + (c & 7)] = (_Float16)val;
        if (c == 0) ws[BA1_OFF + o] = (a1b[o] - a1m[o]) * s + a1t[o];
        return;
    }
    e -= 8192;
    if (e < 16384) {
        int o = e & 127, c = e >> 7;
        float s = a2g[o] * (1.0f / sqrtf(a2v[o] + EPSBN));
        float val = a2w[o * 128 + c] * s;
        ((_Float16*)(ws + A2T_OFF))[o * 128 + (((c >> 3) ^ (o & 7)) * 8) + (c & 7)] = (_Float16)val;
        if (c == 0) ws[BA2_OFF + o] = (a2b[o] - a2m[o]) * s + a2t[o];
        return;
    }
    e -= 16384;
    if (e < 65536) {
        // c2 fragment-linear fp16 image: img[((ot*16+s)*64+l)*8+j]
        int j = e & 7, l = (e >> 3) & 63, s5 = (e >> 9) & 15, ot = e >> 13;
        int o = ot * 32 + (l & 31);
        int c = s5 * 16 + (l >> 5) * 8 + j;
        float sc = c2g[o] * (1.0f / sqrtf(c2v[o] + EPSBN));
        ((_Float16*)(ws + C2T_OFF))[e] = (_Float16)(c2w[o * 256 + c] * sc);
        if (c == 0) ws[BC2_OFF + o] = (c2b[o] - c2m[o]) * sc + c2t[o];
        return;
    }
    e -= 65536;
    if (e < 32768) {
        int j = e & 7, l = (e >> 3) & 63, s5 = (e >> 9) & 15, ot = e >> 13;
        int o = ot * 32 + (l & 31);
        int c = s5 * 16 + (l >> 5) * 8 + j;
        float sc = c3g[o] * (1.0f / sqrtf(c3v[o] + EPSBN));
        ((_Float16*)(ws + C3H_OFF))[e] = (_Float16)(c3w[o * 256 + c] * sc);
        if (c == 0) ws[BC3_OFF + o] = (c3b[o] - c3m[o]) * sc + c3t[o];
        return;
    }
    e -= 32768;
    if (e < 768)        { fold_one(e,          c4w, c4b, nullptr, nullptr, nullptr, nullptr, ws + C4T_OFF, ws + BC4_OFF, 6, 128, 0); return; }
}

// ---------------------------------------------------------------------------
// Kernel 1: per-point MLP 3->64->64 (+ pts4 with exact sq, + q/c for a0 trick)
// ---------------------------------------------------------------------------
__global__ __launch_bounds__(256) void point_mlp_kernel(const float* __restrict__ pts, float* __restrict__ ws)
{
    __shared__ float sh[4][64];
    __shared__ float sx[4][64];
    int lane = threadIdx.x & 63;
    int wv = threadIdx.x >> 6;
    int pid = blockIdx.x * 4 + wv;
    const float* p = pts + pid * 3;
    float x = p[0], y = p[1], z = p[2];
    if (lane == 0) {
        float sq = __fadd_rn(__fadd_rn(__fmul_rn(x, x), __fmul_rn(y, y)), __fmul_rn(z, z));
        ((float4*)(ws + PTS4_OFF))[pid] = make_float4(x, y, z, sq);
    }
    const float* W0T  = ws + W0T_OFF;
    const float* B0   = ws + B0_OFF;
    const float* W1T  = ws + W1T_OFF;
    const float* B1   = ws + B1_OFF;
    const float* A0XT = ws + A0XT_OFF;
    const float* A0FT = ws + A0FT_OFF;
    const float* BA0  = ws + BA0_OFF;

    float h0 = B0[lane];
    h0 = fmaf(x, W0T[lane], h0);
    h0 = fmaf(y, W0T[64 + lane], h0);
    h0 = fmaf(z, W0T[128 + lane], h0);
    h0 = fmaxf(h0, 0.0f);
    sh[wv][lane] = h0;
    __syncthreads();

    float acc = B1[lane];
    #pragma unroll 8
    for (int c = 0; c < 64; ++c) acc = fmaf(W1T[c * 64 + lane], sh[wv][c], acc);
    float x1 = fmaxf(acc, 0.0f);
    sx[wv][lane] = x1;

    float q = __fmul_rn(x, A0XT[lane]);
    q = fmaf(y, A0XT[64 + lane], q);
    q = fmaf(z, A0XT[128 + lane], q);
    ws[Q_OFF + pid * 64 + lane] = q;
    __syncthreads();

    float cacc = q + BA0[lane];
    #pragma unroll 8
    for (int c = 0; c < 64; ++c) cacc = fmaf(A0FT[c * 64 + lane], sx[wv][c], cacc);
    ws[C_OFF + pid * 64 + lane] = cacc;
}

// ---------------------------------------------------------------------------
// Kernel 2: exact kNN, now with full-batch candidate set staged in LDS.
// Selection logic identical to Round 1 (verified). 1 block/CU (105KB LDS).
// ---------------------------------------------------------------------------
__device__ __forceinline__ float dist2_ref(float xn, float yn, float zn, float sqn, float4 pm)
{
    float dot = __fmul_rn(xn, pm.x);
    dot = __fmaf_rn(yn, pm.y, dot);
    dot = __fmaf_rn(zn, pm.z, dot);
    float s = __fadd_rn(sqn, pm.w);
    return __fsub_rn(s, __fmul_rn(2.0f, dot));
}

#define KNN_CAP 64
__global__ __launch_bounds__(512) void knn_kernel(float* __restrict__ ws)
{
    __shared__ __align__(16) float4 sPts[4096];   // 64KB
    __shared__ float gmins[64 * 33];
    __shared__ float bufd[KNN_CAP * 64];
    __shared__ int   bufi[KNN_CAP * 64];
    __shared__ int   cnt[64];
    __shared__ float tau[64];

    const float4* pts4 = (const float4*)(ws + PTS4_OFF);
    int* IDX = (int*)(ws + IDX_OFF);

    int row = threadIdx.x & 63;
    int wv  = threadIdx.x >> 6;
    int base = (blockIdx.x >> 6) << 12;
    int rlocal = (blockIdx.x & 63) * 64 + row;

    // stage 4096 candidates (64KB) coalesced
    #pragma unroll
    for (int u = 0; u < 8; ++u)
        sPts[threadIdx.x + 512 * u] = pts4[base + threadIdx.x + 512 * u];
    if (threadIdx.x < 64) cnt[threadIdx.x] = 0;
    __syncthreads();

    float4 pn = sPts[rlocal];
    float xn = pn.x, yn = pn.y, zn = pn.z, sqn = pn.w;

    // Pass A: minima of 4 contiguous groups of 128 (dual accumulators for ILP)
    #pragma unroll
    for (int g = 0; g < 4; ++g) {
        int m0 = wv * 512 + g * 128;
        float mn0 = INFINITY, mn1 = INFINITY;
        #pragma unroll 8
        for (int i = 0; i < 128; i += 2) {
            mn0 = fminf(mn0, dist2_ref(xn, yn, zn, sqn, sPts[m0 + i]));
            mn1 = fminf(mn1, dist2_ref(xn, yn, zn, sqn, sPts[m0 + i + 1]));
        }
        gmins[row * 33 + wv * 4 + g] = fminf(mn0, mn1);
    }
    __syncthreads();

    // tau = 17th smallest of the 32 group minima
    if (threadIdx.x < 64) {
        int rb = threadIdx.x * 33;
        float tv = 0.0f;
        for (int it = 0; it < 17; ++it) {
            float bm = INFINITY; int bj = 0;
            for (int j = 0; j < 32; ++j) {
                float vv = gmins[rb + j];
                if (vv < bm) { bm = vv; bj = j; }
            }
            gmins[rb + bj] = INFINITY;
            tv = bm;
        }
        tau[threadIdx.x] = tv;
    }
    __syncthreads();

    // Pass B: filter by tau, append (d, m)
    {
        float tv = tau[row];
        int m0 = wv * 512;
        #pragma unroll 4
        for (int i = 0; i < 512; ++i) {
            float d = dist2_ref(xn, yn, zn, sqn, sPts[m0 + i]);
            if (d <= tv) {
                int slot = atomicAdd(&cnt[row], 1);
                if (slot < KNN_CAP) {
                    bufd[slot * 64 + row] = d;
                    bufi[slot * 64 + row] = m0 + i;
                }
            }
        }
    }
    __syncthreads();

    // Extraction: 16 lexicographic (d, idx) minima
    if (threadIdx.x < 64) {
        int rw = threadIdx.x;
        int* out = IDX + (blockIdx.x * 64 + rw) * 16;
        int s = cnt[rw];
        if (s <= KNN_CAP) {
            for (int jj = 0; jj < 16; ++jj) {
                float bd = INFINITY; int bi = 0x7fffffff; int bs = 0;
                for (int t2 = 0; t2 < s; ++t2) {
                    float d = bufd[t2 * 64 + rw];
                    int   i = bufi[t2 * 64 + rw];
                    if (d < bd || (d == bd && i < bi)) { bd = d; bi = i; bs = t2; }
                }
                bufd[bs * 64 + rw] = INFINITY;
                out[jj] = bi;
            }
        } else {
            float xr = sPts[(blockIdx.x & 63) * 64 + rw].x;
            float yr = sPts[(blockIdx.x & 63) * 64 + rw].y;
            float zr = sPts[(blockIdx.x & 63) * 64 + rw].z;
            float sr = sPts[(blockIdx.x & 63) * 64 + rw].w;
            float hd[16]; int hi[16];
            #pragma unroll
            for (int t2 = 0; t2 < 16; ++t2) { hd[t2] = INFINITY; hi[t2] = 0; }
            for (int mm = 0; mm < 4096; ++mm) {
                float d = dist2_ref(xr, yr, zr, sr, sPts[mm]);
                if (d < hd[15]) {
                    float vd = d; int vi = mm;
                    #pragma unroll
                    for (int t2 = 0; t2 < 16; ++t2) {
                        bool sm = vd < hd[t2];
                        float td = hd[t2]; int ti = hi[t2];
                        if (sm) { hd[t2] = vd; hi[t2] = vi; vd = td; vi = ti; }
                    }
                }
            }
            for (int jj = 0; jj < 16; ++jj) out[jj] = hi[jj];
        }
    }
}

// ---------------------------------------------------------------------------
// Kernel 3: a1+a2 fp16 MFMA (unchanged from Round 2 — verified).
// ---------------------------------------------------------------------------
__global__ __launch_bounds__(256) void nbr_mlp_mfma_kernel(float* __restrict__ ws)
{
    __shared__ __align__(16) _Float16 sH1[64 * 128];
    __shared__ __align__(16) _Float16 sWG[16384];
    _Float16* sW1 = sWG;
    _Float16* sG1 = sWG + 8192;
    _Float16* sW2 = sWG;

    const int t   = threadIdx.x;
    const int l   = t & 63;
    const int w   = t >> 6;
    const int ln  = l & 31;
    const int hi  = l >> 5;
    const int blk = blockIdx.x;
    const int gpt0 = blk * 4;
    const int base = (blk >> 10) << 12;

    const float* Cf = ws + C_OFF;
    const float* Qf = ws + Q_OFF;
    const int* IDX = (const int*)(ws + IDX_OFF);
    const float4* w1img = (const float4*)(ws + A1T_OFF);
    const float4* w2img = (const float4*)(ws + A2T_OFF);

    float4 w2r[8];
    #pragma unroll
    for (int u = 0; u < 8; ++u) w2r[u] = w2img[t + 256 * u];

    {
        float4* d = (float4*)sW1;
        #pragma unroll
        for (int u = 0; u < 4; ++u) d[t + 256 * u] = w1img[t + 256 * u];
    }
    {
        int r = t >> 2, cs = t & 3;
        int gpt = gpt0 + (r >> 4);
        int m = IDX[gpt * 16 + (r & 15)];
        const float4* crow = (const float4*)(Cf + (size_t)(base + m) * 64) + cs * 4;
        const float4* qrow = (const float4*)(Qf + (size_t)gpt * 64) + cs * 4;
        v8h h0, h1;
        #pragma unroll
        for (int u = 0; u < 2; ++u) {
            float4 cv = crow[u], qv = qrow[u];
            h0[u * 4 + 0] = (_Float16)fmaxf(cv.x - qv.x, 0.0f);
            h0[u * 4 + 1] = (_Float16)fmaxf(cv.y - qv.y, 0.0f);
            h0[u * 4 + 2] = (_Float16)fmaxf(cv.z - qv.z, 0.0f);
            h0[u * 4 + 3] = (_Float16)fmaxf(cv.w - qv.w, 0.0f);
        }
        #pragma unroll
        for (int u = 0; u < 2; ++u) {
            float4 cv = crow[2 + u], qv = qrow[2 + u];
            h1[u * 4 + 0] = (_Float16)fmaxf(cv.x - qv.x, 0.0f);
            h1[u * 4 + 1] = (_Float16)fmaxf(cv.y - qv.y, 0.0f);
            h1[u * 4 + 2] = (_Float16)fmaxf(cv.z - qv.z, 0.0f);
            h1[u * 4 + 3] = (_Float16)fmaxf(cv.w - qv.w, 0.0f);
        }
        int rs = r & 7;
        *(v8h*)&sG1[r * 64 + ((cs * 2    ) ^ rs) * 8] = h0;
        *(v8h*)&sG1[r * 64 + ((cs * 2 + 1) ^ rs) * 8] = h1;
    }
    float bias1[16], bias2[16];
    #pragma unroll
    for (int i = 0; i < 16; ++i) {
        int ob = w * 32 + (i & 3) + 8 * (i >> 2) + 4 * hi;
        bias1[i] = ws[BA1_OFF + ob];
        bias2[i] = ws[BA2_OFF + ob];
    }
    __syncthreads();

    v8h fa[4];
    {
        int o = w * 32 + ln, os = o & 7;
        #pragma unroll
        for (int kf = 0; kf < 4; ++kf)
            fa[kf] = *(const v8h*)&sW1[o * 64 + ((kf * 2 + hi) ^ os) * 8];
    }
    #pragma unroll
    for (int rt = 0; rt < 2; ++rt) {
        int r = rt * 32 + ln, rs = r & 7;
        v16f acc;
        #pragma unroll
        for (int i = 0; i < 16; ++i) acc[i] = 0.0f;
        #pragma unroll
        for (int kf = 0; kf < 4; ++kf) {
            v8h fb = *(const v8h*)&sG1[r * 64 + ((kf * 2 + hi) ^ rs) * 8];
            acc = __builtin_amdgcn_mfma_f32_32x32x16_f16(fa[kf], fb, acc, 0, 0, 0);
        }
        #pragma unroll
        for (int q = 0; q < 4; ++q) {
            v4h hv;
            #pragma unroll
            for (int j = 0; j < 4; ++j)
                hv[j] = (_Float16)fmaxf(acc[q * 4 + j] + bias1[q * 4 + j], 0.0f);
            int g = w * 4 + q;
            *(v4h*)&sH1[r * 128 + ((g ^ rs) * 8) + 4 * hi] = hv;
        }
    }
    __syncthreads();
    {
        float4* d = (float4*)sW2;
        #pragma unroll
        for (int u = 0; u < 8; ++u) d[t + 256 * u] = w2r[u];
    }
    __syncthreads();

    v8h fa2[8];
    {
        int o = w * 32 + ln, os = o & 7;
        #pragma unroll
        for (int kf = 0; kf < 8; ++kf)
            fa2[kf] = *(const v8h*)&sW2[o * 128 + ((kf * 2 + hi) ^ os) * 8];
    }
    float* LOCAL = ws + LOCAL_OFF;
    #pragma unroll
    for (int rt = 0; rt < 2; ++rt) {
        int r = rt * 32 + ln, rs = r & 7;
        v16f acc;
        #pragma unroll
        for (int i = 0; i < 16; ++i) acc[i] = 0.0f;
        #pragma unroll
        for (int kf = 0; kf < 8; ++kf) {
            v8h fb = *(const v8h*)&sH1[r * 128 + ((kf * 2 + hi) ^ rs) * 8];
            acc = __builtin_amdgcn_mfma_f32_32x32x16_f16(fa2[kf], fb, acc, 0, 0, 0);
        }
        #pragma unroll
        for (int i = 0; i < 16; ++i) {
            float v = acc[i];
            v = fmaxf(v, __shfl_xor(v, 1));
            v = fmaxf(v, __shfl_xor(v, 2));
            v = fmaxf(v, __shfl_xor(v, 4));
            v = fmaxf(v, __shfl_xor(v, 8));
            acc[i] = v;
        }
        if ((l & 15) == 0) {
            int p = gpt0 + rt * 2 + ((l >> 4) & 1);
            #pragma unroll
            for (int q = 0; q < 4; ++q) {
                float4 o4;
                o4.x = fmaxf(acc[q * 4 + 0] + bias2[q * 4 + 0], 0.0f);
                o4.y = fmaxf(acc[q * 4 + 1] + bias2[q * 4 + 1], 0.0f);
                o4.z = fmaxf(acc[q * 4 + 2] + bias2[q * 4 + 2], 0.0f);
                o4.w = fmaxf(acc[q * 4 + 3] + bias2[q * 4 + 3], 0.0f);
                int ob = w * 32 + 8 * q + 4 * hi;
                *(float4*)&LOCAL[(size_t)p * 128 + ob] = o4;
            }
        }
    }
}

// ---------------------------------------------------------------------------
// Kernel 4: global feature = max over N of local.
// ---------------------------------------------------------------------------
__global__ __launch_bounds__(128) void gf_kernel(float* __restrict__ ws)
{
    int b = blockIdx.x, sl = blockIdx.y;
    int c = threadIdx.x;
    const float* LOCAL = ws + LOCAL_OFF + (size_t)(b * 4096 + sl * 128) * 128;
    float m = 0.0f;
    #pragma unroll 4
    for (int i = 0; i < 128; ++i) m = fmaxf(m, LOCAL[i * 128 + c]);
    atomicMax((int*)(ws + GF_OFF) + b * 128 + c, __float_as_int(m));
}

// ---------------------------------------------------------------------------
// Kernel 5 (NEW): head c2/c3 on fp16 MFMA; c4 fp32 VALU epilogue.
// Block 256 (4 waves), 64 points. A = weight frag-images from global (L2),
// B = features in swizzled LDS. c3 output fp32 in LDS (overlays sF).
// ---------------------------------------------------------------------------
__global__ __launch_bounds__(256) void head_mfma_kernel(float* __restrict__ ws, float* __restrict__ out)
{
    __shared__ __align__(16) unsigned char smem[66560];
    _Float16* sF  = (_Float16*)smem;             // [64][256]h swz (c2 B-op)
    float*    sF3 = (float*)smem;                // [64][132]f (c4 input, overlays sF)
    _Float16* sF2 = (_Float16*)(smem + 33792);   // [64][256]h swz (c3 B-op)

    const int t  = threadIdx.x;
    const int l  = t & 63;
    const int w  = t >> 6;
    const int ln = l & 31;
    const int hi = l >> 5;
    const int gpt0 = blockIdx.x * 64;
    const int b = blockIdx.x >> 6;

    const float4* c2h = (const float4*)(ws + C2T_OFF);
    const float4* c3h = (const float4*)(ws + C3H_OFF);

    // stage sF[m][c] fp16: c<128 from LOCAL, c>=128 from GF (broadcast)
    {
        int m = t >> 2, cs = t & 3;
        const float4* src = (cs < 2)
            ? (const float4*)(ws + LOCAL_OFF + (size_t)(gpt0 + m) * 128) + cs * 16
            : (const float4*)(ws + GF_OFF + b * 128) + (cs - 2) * 16;
        int c0 = cs * 64;
        #pragma unroll
        for (int u = 0; u < 8; ++u) {
            float4 a0 = src[u * 2], a1 = src[u * 2 + 1];
            v8h h;
            h[0] = (_Float16)a0.x; h[1] = (_Float16)a0.y;
            h[2] = (_Float16)a0.z; h[3] = (_Float16)a0.w;
            h[4] = (_Float16)a1.x; h[5] = (_Float16)a1.y;
            h[6] = (_Float16)a1.z; h[7] = (_Float16)a1.w;
            int g = ((c0 >> 3) + u) ^ (m & 31);
            *(v8h*)&sF[m * 256 + g * 8] = h;
        }
    }
    __syncthreads();

    // ---- c2: out 256, wave w handles o-tiles {2w, 2w+1} ----
    #pragma unroll
    for (int ot = 0; ot < 2; ++ot) {
        int ot2 = 2 * w + ot;
        v8h fa[16];
        #pragma unroll
        for (int s = 0; s < 16; ++s) {
            float4 tmp = c2h[(ot2 * 16 + s) * 64 + l];
            fa[s] = *(v8h*)&tmp;
        }
        float b2[16];
        #pragma unroll
        for (int i = 0; i < 16; ++i)
            b2[i] = ws[BC2_OFF + ot2 * 32 + (i & 3) + 8 * (i >> 2) + 4 * hi];
        #pragma unroll
        for (int mt = 0; mt < 2; ++mt) {
            int m = mt * 32 + ln;
            v16f acc;
            #pragma unroll
            for (int i = 0; i < 16; ++i) acc[i] = 0.0f;
            #pragma unroll
            for (int s = 0; s < 16; ++s) {
                v8h fb = *(const v8h*)&sF[m * 256 + (((2 * s + hi) ^ ln) * 8)];
                acc = __builtin_amdgcn_mfma_f32_32x32x16_f16(fa[s], fb, acc, 0, 0, 0);
            }
            #pragma unroll
            for (int q = 0; q < 4; ++q) {
                v4h hv;
                #pragma unroll
                for (int j = 0; j < 4; ++j)
                    hv[j] = (_Float16)fmaxf(acc[q * 4 + j] + b2[q * 4 + j], 0.0f);
                *(v4h*)&sF2[m * 256 + (((ot2 * 4 + q) ^ ln) * 8) + 4 * hi] = hv;
            }
        }
    }
    __syncthreads();

    // ---- c3: out 128, wave w handles o-tile w ----
    {
        v8h fa[16];
        #pragma unroll
        for (int s = 0; s < 16; ++s) {
            float4 tmp = c3h[(w * 16 + s) * 64 + l];
            fa[s] = *(v8h*)&tmp;
        }
        float b3[16];
        #pragma unroll
        for (int i = 0; i < 16; ++i)
            b3[i] = ws[BC3_OFF + w * 32 + (i & 3) + 8 * (i >> 2) + 4 * hi];
        #pragma unroll
        for (int mt = 0; mt < 2; ++mt) {
            int m = mt * 32 + ln;
            v16f acc;
            #pragma unroll
            for (int i = 0; i < 16; ++i) acc[i] = 0.0f;
            #pragma unroll
            for (int s = 0; s < 16; ++s) {
                v8h fb = *(const v8h*)&sF2[m * 256 + (((2 * s + hi) ^ ln) * 8)];
                acc = __builtin_amdgcn_mfma_f32_32x32x16_f16(fa[s], fb, acc, 0, 0, 0);
            }
            #pragma unroll
            for (int q = 0; q < 4; ++q) {
                float4 hv;
                hv.x = fmaxf(acc[q * 4 + 0] + b3[q * 4 + 0], 0.0f);
                hv.y = fmaxf(acc[q * 4 + 1] + b3[q * 4 + 1], 0.0f);
                hv.z = fmaxf(acc[q * 4 + 2] + b3[q * 4 + 2], 0.0f);
                hv.w = fmaxf(acc[q * 4 + 3] + b3[q * 4 + 3], 0.0f);
                *(float4*)&sF3[m * 132 + w * 32 + q * 8 + 4 * hi] = hv;
            }
        }
    }
    __syncthreads();

    // ---- c4: 128 -> 6 fp32 ----
    const float* C4T = ws + C4T_OFF;
    for (int mo = t; mo < 384; mo += 256) {
        int m = mo / 6, o = mo - m * 6;
        float a = ws[BC4_OFF + o];
        const float4* f4 = (const float4*)(sF3 + m * 132);
        #pragma unroll 8
        for (int kq = 0; kq < 32; ++kq) {
            float4 f = f4[kq];
            a = fmaf(f.x, C4T[(kq * 4 + 0) * 6 + o], a);
            a = fmaf(f.y, C4T[(kq * 4 + 1) * 6 + o], a);
            a = fmaf(f.z, C4T[(kq * 4 + 2) * 6 + o], a);
            a = fmaf(f.w, C4T[(kq * 4 + 3) * 6 + o], a);
        }
        out[(size_t)(gpt0 + m) * 6 + o] = a;
    }
}

// ---------------------------------------------------------------------------
extern "C" void kernel_launch(void* const* d_in, const int* in_sizes, int n_in,
                              void* d_out, int out_size, void* d_ws, size_t ws_size,
                              hipStream_t stream)
{
    const float* pts = (const float*)d_in[0];
    float* ws = (float*)d_ws;
    float* out = (float*)d_out;

    hipMemsetAsync(ws + GF_OFF, 0, 1024 * sizeof(float), stream);

    fold_kernel<<<517, 256, 0, stream>>>(
        (const float*)d_in[1],  (const float*)d_in[2],  (const float*)d_in[3],  (const float*)d_in[4],  (const float*)d_in[5],  (const float*)d_in[6],
        (const float*)d_in[7],  (const float*)d_in[8],  (const float*)d_in[9],  (const float*)d_in[10], (const float*)d_in[11], (const float*)d_in[12],
        (const float*)d_in[13], (const float*)d_in[14], (const float*)d_in[15], (const float*)d_in[16], (const float*)d_in[17], (const float*)d_in[18],
        (const float*)d_in[19], (const float*)d_in[20], (const float*)d_in[21], (const float*)d_in[22], (const float*)d_in[23], (const float*)d_in[24],
        (const float*)d_in[25], (const float*)d_in[26], (const float*)d_in[27], (const float*)d_in[28], (const float*)d_in[29], (const float*)d_in[30],
        (const float*)d_in[31], (const float*)d_in[32], (const float*)d_in[33], (const float*)d_in[34], (const float*)d_in[35], (const float*)d_in[36],
        (const float*)d_in[37], (const float*)d_in[38], (const float*)d_in[39], (const float*)d_in[40], (const float*)d_in[41], (const float*)d_in[42],
        (const float*)d_in[43], (const float*)d_in[44],
        ws);

    point_mlp_kernel<<<8192, 256, 0, stream>>>(pts, ws);
    knn_kernel<<<512, 512, 0, stream>>>(ws);
    nbr_mlp_mfma_kernel<<<8192, 256, 0, stream>>>(ws);
    gf_kernel<<<dim3(8, 32), 128, 0, stream>>>(ws);
    head_mfma_kernel<<<512, 256, 0, stream>>>(ws, out);
}

// Round 4
// 474.054 us; speedup vs baseline: 1.7875x; 1.1926x over previous
//
#include <hip/hip_runtime.h>
#include <math.h>

// ============================================================================
// Round 4: knn rewritten — candidates fetched via wave-uniform SCALAR loads
// (s_load_dwordx4 into SGPRs), no candidate LDS at all. LDS = selection state
// only (~38KB) -> 4 blocks/CU, 32 waves/CU. tau = 17th of 64 group minima.
// Everything else unchanged from Round 3 (verified, absmax 2.44e-4).
// ============================================================================

#define EPSBN 1e-5f

typedef _Float16 v8h  __attribute__((ext_vector_type(8)));
typedef _Float16 v4h  __attribute__((ext_vector_type(4)));
typedef float    v16f __attribute__((ext_vector_type(16)));

// ---- ws layout (float offsets) ----
#define W0T_OFF   0         // [3][64]
#define B0_OFF    192
#define W1T_OFF   256       // [64][64]
#define B1_OFF    4352
#define A0XT_OFF  4416      // [3][64]
#define A0FT_OFF  4608      // [64][64]
#define BA0_OFF   8704
#define A1T_OFF   8768      // fp16 image [128][64]h swizzled (8192 halfs)
#define BA1_OFF   16960
#define A2T_OFF   17088     // fp16 image [128][128]h swizzled (16384 halfs)
#define BA2_OFF   33472
#define C2T_OFF   33600     // fp16 frag-linear c2 image: 8192 float4 (65536 h)
#define C3H_OFF   66368     // fp16 frag-linear c3 image: 4096 float4 (32768 h)
#define BC2_OFF   99136
#define BC3_OFF   132160
#define C4T_OFF   132288    // [128][6] fp32
#define BC4_OFF   133056
#define PTS4_OFF  133120    // [32768] float4 {x,y,z,sq}
#define Q_OFF     264192    // [32768][64]
#define C_OFF     2361344   // [32768][64]
#define IDX_OFF   4458496   // [32768][16] int (batch-local m)
#define LOCAL_OFF 4982784   // [32768][128]
#define GF_OFF    9177088   // [8][128]

// ---------------------------------------------------------------------------
// Kernel 0: fold BN into weights.
// ---------------------------------------------------------------------------
__device__ __forceinline__ void fold_one(int e, const float* w, const float* b,
    const float* g, const float* t, const float* m, const float* v,
    float* wt, float* bo, int O, int Cfull, int cbeg)
{
    int o = e % O, c = e / O;
    float s = 1.0f;
    if (g) s = g[o] * (1.0f / sqrtf(v[o] + EPSBN));
    wt[c * O + o] = w[o * Cfull + cbeg + c] * s;
    if (c == 0 && bo) {
        float bias = b[o];
        if (g) bias = (bias - m[o]) * s + t[o];
        bo[o] = bias;
    }
}

__global__ __launch_bounds__(256) void fold_kernel(
    const float* c0w, const float* c0b, const float* c0g, const float* c0t, const float* c0m, const float* c0v,
    const float* c1w, const float* c1b, const float* c1g, const float* c1t, const float* c1m, const float* c1v,
    const float* a0w, const float* a0b, const float* a0g, const float* a0t, const float* a0m, const float* a0v,
    const float* a1w, const float* a1b, const float* a1g, const float* a1t, const float* a1m, const float* a1v,
    const float* a2w, const float* a2b, const float* a2g, const float* a2t, const float* a2m, const float* a2v,
    const float* c2w, const float* c2b, const float* c2g, const float* c2t, const float* c2m, const float* c2v,
    const float* c3w, const float* c3b, const float* c3g, const float* c3t, const float* c3m, const float* c3v,
    const float* c4w, const float* c4b,
    float* ws)
{
    int e = blockIdx.x * 256 + threadIdx.x;
    if (e < 192)        { fold_one(e,          c0w, c0b, c0g, c0t, c0m, c0v, ws + W0T_OFF,  ws + B0_OFF,  64, 3,   0); return; }
    e -= 192;
    if (e < 4096)       { fold_one(e,          c1w, c1b, c1g, c1t, c1m, c1v, ws + W1T_OFF,  ws + B1_OFF,  64, 64,  0); return; }
    e -= 4096;
    if (e < 192)        { fold_one(e,          a0w, a0b, a0g, a0t, a0m, a0v, ws + A0XT_OFF, ws + BA0_OFF, 64, 67,  0); return; }
    e -= 192;
    if (e < 4096)       { fold_one(e,          a0w, a0b, a0g, a0t, a0m, a0v, ws + A0FT_OFF, nullptr,      64, 67,  3); return; }
    e -= 4096;
    if (e < 8192) {
        int o = e & 127, c = e >> 7;
        float s = a1g[o] * (1.0f / sqrtf(a1v[o] + EPSBN));
        float val = a1w[o * 64 + c] * s;
        ((_Float16*)(ws + A1T_OFF))[o * 64 + (((c >> 3) ^ (o & 7)) * 8) + (c & 7)] = (_Float16)val;
        if (c == 0) ws[BA1_OFF + o] = (a1b[o] - a1m[o]) * s + a1t[o];
        return;
    }
    e -= 8192;
    if (e < 16384) {
        int o = e & 127, c = e >> 7;
        float s = a2g[o] * (1.0f / sqrtf(a2v[o] + EPSBN));
        float val = a2w[o * 128 + c] * s;
        ((_Float16*)(ws + A2T_OFF))[o * 128 + (((c >> 3) ^ (o & 7)) * 8) + (c & 7)] = (_Float16)val;
        if (c == 0) ws[BA2_OFF + o] = (a2b[o] - a2m[o]) * s + a2t[o];
        return;
    }
    e -= 16384;
    if (e < 65536) {
        int j = e & 7, l = (e >> 3) & 63, s5 = (e >> 9) & 15, ot = e >> 13;
        int o = ot * 32 + (l & 31);
        int c = s5 * 16 + (l >> 5) * 8 + j;
        float sc = c2g[o] * (1.0f / sqrtf(c2v[o] + EPSBN));
        ((_Float16*)(ws + C2T_OFF))[e] = (_Float16)(c2w[o * 256 + c] * sc);
        if (c == 0) ws[BC2_OFF + o] = (c2b[o] - c2m[o]) * sc + c2t[o];
        return;
    }
    e -= 65536;
    if (e < 32768) {
        int j = e & 7, l = (e >> 3) & 63, s5 = (e >> 9) & 15, ot = e >> 13;
        int o = ot * 32 + (l & 31);
        int c = s5 * 16 + (l >> 5) * 8 + j;
        float sc = c3g[o] * (1.0f / sqrtf(c3v[o] + EPSBN));
        ((_Float16*)(ws + C3H_OFF))[e] = (_Float16)(c3w[o * 256 + c] * sc);
        if (c == 0) ws[BC3_OFF + o] = (c3b[o] - c3m[o]) * sc + c3t[o];
        return;
    }
    e -= 32768;
    if (e < 768)        { fold_one(e,          c4w, c4b, nullptr, nullptr, nullptr, nullptr, ws + C4T_OFF, ws + BC4_OFF, 6, 128, 0); return; }
}

// ---------------------------------------------------------------------------
// Kernel 1: per-point MLP 3->64->64 (+ pts4 with exact sq, + q/c for a0 trick)
// ---------------------------------------------------------------------------
__global__ __launch_bounds__(256) void point_mlp_kernel(const float* __restrict__ pts, float* __restrict__ ws)
{
    __shared__ float sh[4][64];
    __shared__ float sx[4][64];
    int lane = threadIdx.x & 63;
    int wv = threadIdx.x >> 6;
    int pid = blockIdx.x * 4 + wv;
    const float* p = pts + pid * 3;
    float x = p[0], y = p[1], z = p[2];
    if (lane == 0) {
        float sq = __fadd_rn(__fadd_rn(__fmul_rn(x, x), __fmul_rn(y, y)), __fmul_rn(z, z));
        ((float4*)(ws + PTS4_OFF))[pid] = make_float4(x, y, z, sq);
    }
    const float* W0T  = ws + W0T_OFF;
    const float* B0   = ws + B0_OFF;
    const float* W1T  = ws + W1T_OFF;
    const float* B1   = ws + B1_OFF;
    const float* A0XT = ws + A0XT_OFF;
    const float* A0FT = ws + A0FT_OFF;
    const float* BA0  = ws + BA0_OFF;

    float h0 = B0[lane];
    h0 = fmaf(x, W0T[lane], h0);
    h0 = fmaf(y, W0T[64 + lane], h0);
    h0 = fmaf(z, W0T[128 + lane], h0);
    h0 = fmaxf(h0, 0.0f);
    sh[wv][lane] = h0;
    __syncthreads();

    float acc = B1[lane];
    #pragma unroll 8
    for (int c = 0; c < 64; ++c) acc = fmaf(W1T[c * 64 + lane], sh[wv][c], acc);
    float x1 = fmaxf(acc, 0.0f);
    sx[wv][lane] = x1;

    float q = __fmul_rn(x, A0XT[lane]);
    q = fmaf(y, A0XT[64 + lane], q);
    q = fmaf(z, A0XT[128 + lane], q);
    ws[Q_OFF + pid * 64 + lane] = q;
    __syncthreads();

    float cacc = q + BA0[lane];
    #pragma unroll 8
    for (int c = 0; c < 64; ++c) cacc = fmaf(A0FT[c * 64 + lane], sx[wv][c], cacc);
    ws[C_OFF + pid * 64 + lane] = cacc;
}

// ---------------------------------------------------------------------------
// Kernel 2: exact kNN via wave-uniform SCALAR candidate loads.
// Block 512 (8 waves, 64 rows). Wave wv scans candidates [wv*512, wv*512+512)
// in 8 groups of 64. tau = 17th smallest of 64 group minima (>= d_(16):
// at most 15 group-minima can be < d_(16) since any element < d_(16) is
// itself a top-15 member). Filter-append, lexicographic extraction.
// ---------------------------------------------------------------------------
__device__ __forceinline__ float dist2_ref(float xn, float yn, float zn, float sqn, float4 pm)
{
    float dot = __fmul_rn(xn, pm.x);
    dot = __fmaf_rn(yn, pm.y, dot);
    dot = __fmaf_rn(zn, pm.z, dot);
    float s = __fadd_rn(sqn, pm.w);
    return __fsub_rn(s, __fmul_rn(2.0f, dot));
}

#define KNN_CAP 40
__global__ __launch_bounds__(512) void knn_kernel(float* __restrict__ ws)
{
    __shared__ float gmins[64 * 65];          // 16.6KB
    __shared__ float bufd[KNN_CAP * 64];      // 10.2KB
    __shared__ int   bufi[KNN_CAP * 64];      // 10.2KB
    __shared__ int   cnt[64];
    __shared__ float tau[64];

    const float4* __restrict__ pts4 = (const float4*)(ws + PTS4_OFF);
    int* IDX = (int*)(ws + IDX_OFF);

    const int row  = threadIdx.x & 63;
    const int wvu  = __builtin_amdgcn_readfirstlane(threadIdx.x >> 6); // uniform!
    const int base = (blockIdx.x >> 6) << 12;                           // uniform
    const int r    = blockIdx.x * 64 + row;

    if (threadIdx.x < 64) cnt[threadIdx.x] = 0;

    float4 pn = pts4[r];
    float xn = pn.x, yn = pn.y, zn = pn.z, sqn = pn.w;

    // Pass A: 8 groups of 64, minima via 4 interleaved accumulators.
    // Candidate address is wave-uniform -> s_load_dwordx4 (SGPR operands).
    #pragma unroll
    for (int g = 0; g < 8; ++g) {
        const float4* __restrict__ cp = pts4 + base + wvu * 512 + g * 64;
        float mn0 = INFINITY, mn1 = INFINITY, mn2 = INFINITY, mn3 = INFINITY;
        #pragma unroll 4
        for (int i = 0; i < 64; i += 4) {
            mn0 = fminf(mn0, dist2_ref(xn, yn, zn, sqn, cp[i + 0]));
            mn1 = fminf(mn1, dist2_ref(xn, yn, zn, sqn, cp[i + 1]));
            mn2 = fminf(mn2, dist2_ref(xn, yn, zn, sqn, cp[i + 2]));
            mn3 = fminf(mn3, dist2_ref(xn, yn, zn, sqn, cp[i + 3]));
        }
        gmins[row * 65 + wvu * 8 + g] = fminf(fminf(mn0, mn1), fminf(mn2, mn3));
    }
    __syncthreads();

    // tau = 17th smallest of the 64 group minima (wave 0, lane = row)
    if (threadIdx.x < 64) {
        int rb = threadIdx.x * 65;
        float tv = 0.0f;
        for (int it = 0; it < 17; ++it) {
            float bm = INFINITY; int bj = 0;
            #pragma unroll 8
            for (int j = 0; j < 64; ++j) {
                float vv = gmins[rb + j];
                if (vv < bm) { bm = vv; bj = j; }
            }
            gmins[rb + bj] = INFINITY;
            tv = bm;
        }
        tau[threadIdx.x] = tv;
    }
    __syncthreads();

    // Pass B: filter by tau, append (d, local m) to per-row buffer
    {
        float tv = tau[row];
        const float4* __restrict__ cp = pts4 + base + wvu * 512;
        #pragma unroll 4
        for (int i = 0; i < 512; ++i) {
            float d = dist2_ref(xn, yn, zn, sqn, cp[i]);
            if (d <= tv) {
                int slot = atomicAdd(&cnt[row], 1);
                if (slot < KNN_CAP) {
                    bufd[slot * 64 + row] = d;
                    bufi[slot * 64 + row] = wvu * 512 + i;
                }
            }
        }
    }
    __syncthreads();

    // Extraction: 16 lexicographic (d, idx) minima -> matches stable top_k
    if (threadIdx.x < 64) {
        int rw = threadIdx.x;
        int* out = IDX + (blockIdx.x * 64 + rw) * 16;
        int s = cnt[rw];
        if (s <= KNN_CAP) {
            for (int jj = 0; jj < 16; ++jj) {
                float bd = INFINITY; int bi = 0x7fffffff; int bs = 0;
                for (int t2 = 0; t2 < s; ++t2) {
                    float d = bufd[t2 * 64 + rw];
                    int   i = bufi[t2 * 64 + rw];
                    if (d < bd || (d == bd && i < bi)) { bd = d; bi = i; bs = t2; }
                }
                bufd[bs * 64 + rw] = INFINITY;
                out[jj] = bi;
            }
        } else {
            // overflow fallback (rare): exact serial top-16 for this row
            float hd[16]; int hi[16];
            #pragma unroll
            for (int t2 = 0; t2 < 16; ++t2) { hd[t2] = INFINITY; hi[t2] = 0; }
            for (int mm = 0; mm < 4096; ++mm) {
                float d = dist2_ref(xn, yn, zn, sqn, pts4[base + mm]);
                if (d < hd[15]) {
                    float vd = d; int vi = mm;
                    #pragma unroll
                    for (int t2 = 0; t2 < 16; ++t2) {
                        bool sm = vd < hd[t2];
                        float td = hd[t2]; int ti = hi[t2];
                        if (sm) { hd[t2] = vd; hi[t2] = vi; vd = td; vi = ti; }
                    }
                }
            }
            for (int jj = 0; jj < 16; ++jj) out[jj] = hi[jj];
        }
    }
}

// ---------------------------------------------------------------------------
// Kernel 3: a1+a2 fp16 MFMA (unchanged — verified).
// ---------------------------------------------------------------------------
__global__ __launch_bounds__(256) void nbr_mlp_mfma_kernel(float* __restrict__ ws)
{
    __shared__ __align__(16) _Float16 sH1[64 * 128];
    __shared__ __align__(16) _Float16 sWG[16384];
    _Float16* sW1 = sWG;
    _Float16* sG1 = sWG + 8192;
    _Float16* sW2 = sWG;

    const int t   = threadIdx.x;
    const int l   = t & 63;
    const int w   = t >> 6;
    const int ln  = l & 31;
    const int hi  = l >> 5;
    const int blk = blockIdx.x;
    const int gpt0 = blk * 4;
    const int base = (blk >> 10) << 12;

    const float* Cf = ws + C_OFF;
    const float* Qf = ws + Q_OFF;
    const int* IDX = (const int*)(ws + IDX_OFF);
    const float4* w1img = (const float4*)(ws + A1T_OFF);
    const float4* w2img = (const float4*)(ws + A2T_OFF);

    float4 w2r[8];
    #pragma unroll
    for (int u = 0; u < 8; ++u) w2r[u] = w2img[t + 256 * u];

    {
        float4* d = (float4*)sW1;
        #pragma unroll
        for (int u = 0; u < 4; ++u) d[t + 256 * u] = w1img[t + 256 * u];
    }
    {
        int r = t >> 2, cs = t & 3;
        int gpt = gpt0 + (r >> 4);
        int m = IDX[gpt * 16 + (r & 15)];
        const float4* crow = (const float4*)(Cf + (size_t)(base + m) * 64) + cs * 4;
        const float4* qrow = (const float4*)(Qf + (size_t)gpt * 64) + cs * 4;
        v8h h0, h1;
        #pragma unroll
        for (int u = 0; u < 2; ++u) {
            float4 cv = crow[u], qv = qrow[u];
            h0[u * 4 + 0] = (_Float16)fmaxf(cv.x - qv.x, 0.0f);
            h0[u * 4 + 1] = (_Float16)fmaxf(cv.y - qv.y, 0.0f);
            h0[u * 4 + 2] = (_Float16)fmaxf(cv.z - qv.z, 0.0f);
            h0[u * 4 + 3] = (_Float16)fmaxf(cv.w - qv.w, 0.0f);
        }
        #pragma unroll
        for (int u = 0; u < 2; ++u) {
            float4 cv = crow[2 + u], qv = qrow[2 + u];
            h1[u * 4 + 0] = (_Float16)fmaxf(cv.x - qv.x, 0.0f);
            h1[u * 4 + 1] = (_Float16)fmaxf(cv.y - qv.y, 0.0f);
            h1[u * 4 + 2] = (_Float16)fmaxf(cv.z - qv.z, 0.0f);
            h1[u * 4 + 3] = (_Float16)fmaxf(cv.w - qv.w, 0.0f);
        }
        int rs = r & 7;
        *(v8h*)&sG1[r * 64 + ((cs * 2    ) ^ rs) * 8] = h0;
        *(v8h*)&sG1[r * 64 + ((cs * 2 + 1) ^ rs) * 8] = h1;
    }
    float bias1[16], bias2[16];
    #pragma unroll
    for (int i = 0; i < 16; ++i) {
        int ob = w * 32 + (i & 3) + 8 * (i >> 2) + 4 * hi;
        bias1[i] = ws[BA1_OFF + ob];
        bias2[i] = ws[BA2_OFF + ob];
    }
    __syncthreads();

    v8h fa[4];
    {
        int o = w * 32 + ln, os = o & 7;
        #pragma unroll
        for (int kf = 0; kf < 4; ++kf)
            fa[kf] = *(const v8h*)&sW1[o * 64 + ((kf * 2 + hi) ^ os) * 8];
    }
    #pragma unroll
    for (int rt = 0; rt < 2; ++rt) {
        int r = rt * 32 + ln, rs = r & 7;
        v16f acc;
        #pragma unroll
        for (int i = 0; i < 16; ++i) acc[i] = 0.0f;
        #pragma unroll
        for (int kf = 0; kf < 4; ++kf) {
            v8h fb = *(const v8h*)&sG1[r * 64 + ((kf * 2 + hi) ^ rs) * 8];
            acc = __builtin_amdgcn_mfma_f32_32x32x16_f16(fa[kf], fb, acc, 0, 0, 0);
        }
        #pragma unroll
        for (int q = 0; q < 4; ++q) {
            v4h hv;
            #pragma unroll
            for (int j = 0; j < 4; ++j)
                hv[j] = (_Float16)fmaxf(acc[q * 4 + j] + bias1[q * 4 + j], 0.0f);
            int g = w * 4 + q;
            *(v4h*)&sH1[r * 128 + ((g ^ rs) * 8) + 4 * hi] = hv;
        }
    }
    __syncthreads();
    {
        float4* d = (float4*)sW2;
        #pragma unroll
        for (int u = 0; u < 8; ++u) d[t + 256 * u] = w2r[u];
    }
    __syncthreads();

    v8h fa2[8];
    {
        int o = w * 32 + ln, os = o & 7;
        #pragma unroll
        for (int kf = 0; kf < 8; ++kf)
            fa2[kf] = *(const v8h*)&sW2[o * 128 + ((kf * 2 + hi) ^ os) * 8];
    }
    float* LOCAL = ws + LOCAL_OFF;
    #pragma unroll
    for (int rt = 0; rt < 2; ++rt) {
        int r = rt * 32 + ln, rs = r & 7;
        v16f acc;
        #pragma unroll
        for (int i = 0; i < 16; ++i) acc[i] = 0.0f;
        #pragma unroll
        for (int kf = 0; kf < 8; ++kf) {
            v8h fb = *(const v8h*)&sH1[r * 128 + ((kf * 2 + hi) ^ rs) * 8];
            acc = __builtin_amdgcn_mfma_f32_32x32x16_f16(fa2[kf], fb, acc, 0, 0, 0);
        }
        #pragma unroll
        for (int i = 0; i < 16; ++i) {
            float v = acc[i];
            v = fmaxf(v, __shfl_xor(v, 1));
            v = fmaxf(v, __shfl_xor(v, 2));
            v = fmaxf(v, __shfl_xor(v, 4));
            v = fmaxf(v, __shfl_xor(v, 8));
            acc[i] = v;
        }
        if ((l & 15) == 0) {
            int p = gpt0 + rt * 2 + ((l >> 4) & 1);
            #pragma unroll
            for (int q = 0; q < 4; ++q) {
                float4 o4;
                o4.x = fmaxf(acc[q * 4 + 0] + bias2[q * 4 + 0], 0.0f);
                o4.y = fmaxf(acc[q * 4 + 1] + bias2[q * 4 + 1], 0.0f);
                o4.z = fmaxf(acc[q * 4 + 2] + bias2[q * 4 + 2], 0.0f);
                o4.w = fmaxf(acc[q * 4 + 3] + bias2[q * 4 + 3], 0.0f);
                int ob = w * 32 + 8 * q + 4 * hi;
                *(float4*)&LOCAL[(size_t)p * 128 + ob] = o4;
            }
        }
    }
}

// ---------------------------------------------------------------------------
// Kernel 4: global feature = max over N of local.
// ---------------------------------------------------------------------------
__global__ __launch_bounds__(128) void gf_kernel(float* __restrict__ ws)
{
    int b = blockIdx.x, sl = blockIdx.y;
    int c = threadIdx.x;
    const float* LOCAL = ws + LOCAL_OFF + (size_t)(b * 4096 + sl * 128) * 128;
    float m = 0.0f;
    #pragma unroll 4
    for (int i = 0; i < 128; ++i) m = fmaxf(m, LOCAL[i * 128 + c]);
    atomicMax((int*)(ws + GF_OFF) + b * 128 + c, __float_as_int(m));
}

// ---------------------------------------------------------------------------
// Kernel 5: head c2/c3 fp16 MFMA + c4 fp32 (unchanged — verified).
// ---------------------------------------------------------------------------
__global__ __launch_bounds__(256) void head_mfma_kernel(float* __restrict__ ws, float* __restrict__ out)
{
    __shared__ __align__(16) unsigned char smem[66560];
    _Float16* sF  = (_Float16*)smem;
    float*    sF3 = (float*)smem;
    _Float16* sF2 = (_Float16*)(smem + 33792);

    const int t  = threadIdx.x;
    const int l  = t & 63;
    const int w  = t >> 6;
    const int ln = l & 31;
    const int hi = l >> 5;
    const int gpt0 = blockIdx.x * 64;
    const int b = blockIdx.x >> 6;

    const float4* c2h = (const float4*)(ws + C2T_OFF);
    const float4* c3h = (const float4*)(ws + C3H_OFF);

    {
        int m = t >> 2, cs = t & 3;
        const float4* src = (cs < 2)
            ? (const float4*)(ws + LOCAL_OFF + (size_t)(gpt0 + m) * 128) + cs * 16
            : (const float4*)(ws + GF_OFF + b * 128) + (cs - 2) * 16;
        int c0 = cs * 64;
        #pragma unroll
        for (int u = 0; u < 8; ++u) {
            float4 a0 = src[u * 2], a1 = src[u * 2 + 1];
            v8h h;
            h[0] = (_Float16)a0.x; h[1] = (_Float16)a0.y;
            h[2] = (_Float16)a0.z; h[3] = (_Float16)a0.w;
            h[4] = (_Float16)a1.x; h[5] = (_Float16)a1.y;
            h[6] = (_Float16)a1.z; h[7] = (_Float16)a1.w;
            int g = ((c0 >> 3) + u) ^ (m & 31);
            *(v8h*)&sF[m * 256 + g * 8] = h;
        }
    }
    __syncthreads();

    #pragma unroll
    for (int ot = 0; ot < 2; ++ot) {
        int ot2 = 2 * w + ot;
        v8h fa[16];
        #pragma unroll
        for (int s = 0; s < 16; ++s) {
            float4 tmp = c2h[(ot2 * 16 + s) * 64 + l];
            fa[s] = *(v8h*)&tmp;
        }
        float b2[16];
        #pragma unroll
        for (int i = 0; i < 16; ++i)
            b2[i] = ws[BC2_OFF + ot2 * 32 + (i & 3) + 8 * (i >> 2) + 4 * hi];
        #pragma unroll
        for (int mt = 0; mt < 2; ++mt) {
            int m = mt * 32 + ln;
            v16f acc;
            #pragma unroll
            for (int i = 0; i < 16; ++i) acc[i] = 0.0f;
            #pragma unroll
            for (int s = 0; s < 16; ++s) {
                v8h fb = *(const v8h*)&sF[m * 256 + (((2 * s + hi) ^ ln) * 8)];
                acc = __builtin_amdgcn_mfma_f32_32x32x16_f16(fa[s], fb, acc, 0, 0, 0);
            }
            #pragma unroll
            for (int q = 0; q < 4; ++q) {
                v4h hv;
                #pragma unroll
                for (int j = 0; j < 4; ++j)
                    hv[j] = (_Float16)fmaxf(acc[q * 4 + j] + b2[q * 4 + j], 0.0f);
                *(v4h*)&sF2[m * 256 + (((ot2 * 4 + q) ^ ln) * 8) + 4 * hi] = hv;
            }
        }
    }
    __syncthreads();

    {
        v8h fa[16];
        #pragma unroll
        for (int s = 0; s < 16; ++s) {
            float4 tmp = c3h[(w * 16 + s) * 64 + l];
            fa[s] = *(v8h*)&tmp;
        }
        float b3[16];
        #pragma unroll
        for (int i = 0; i < 16; ++i)
            b3[i] = ws[BC3_OFF + w * 32 + (i & 3) + 8 * (i >> 2) + 4 * hi];
        #pragma unroll
        for (int mt = 0; mt < 2; ++mt) {
            int m = mt * 32 + ln;
            v16f acc;
            #pragma unroll
            for (int i = 0; i < 16; ++i) acc[i] = 0.0f;
            #pragma unroll
            for (int s = 0; s < 16; ++s) {
                v8h fb = *(const v8h*)&sF2[m * 256 + (((2 * s + hi) ^ ln) * 8)];
                acc = __builtin_amdgcn_mfma_f32_32x32x16_f16(fa[s], fb, acc, 0, 0, 0);
            }
            #pragma unroll
            for (int q = 0; q < 4; ++q) {
                float4 hv;
                hv.x = fmaxf(acc[q * 4 + 0] + b3[q * 4 + 0], 0.0f);
                hv.y = fmaxf(acc[q * 4 + 1] + b3[q * 4 + 1], 0.0f);
                hv.z = fmaxf(acc[q * 4 + 2] + b3[q * 4 + 2], 0.0f);
                hv.w = fmaxf(acc[q * 4 + 3] + b3[q * 4 + 3], 0.0f);
                *(float4*)&sF3[m * 132 + w * 32 + q * 8 + 4 * hi] = hv;
            }
        }
    }
    __syncthreads();

    const float* C4T = ws + C4T_OFF;
    for (int mo = t; mo < 384; mo += 256) {
        int m = mo / 6, o = mo - m * 6;
        float a = ws[BC4_OFF + o];
        const float4* f4 = (const float4*)(sF3 + m * 132);
        #pragma unroll 8
        for (int kq = 0; kq < 32; ++kq) {
            float4 f = f4[kq];
            a = fmaf(f.x, C4T[(kq * 4 + 0) * 6 + o], a);
            a = fmaf(f.y, C4T[(kq * 4 + 1) * 6 + o], a);
            a = fmaf(f.z, C4T[(kq * 4 + 2) * 6 + o], a);
            a = fmaf(f.w, C4T[(kq * 4 + 3) * 6 + o], a);
        }
        out[(size_t)(gpt0 + m) * 6 + o] = a;
    }
}

// ---------------------------------------------------------------------------
extern "C" void kernel_launch(void* const* d_in, const int* in_sizes, int n_in,
                              void* d_out, int out_size, void* d_ws, size_t ws_size,
                              hipStream_t stream)
{
    const float* pts = (const float*)d_in[0];
    float* ws = (float*)d_ws;
    float* out = (float*)d_out;

    hipMemsetAsync(ws + GF_OFF, 0, 1024 * sizeof(float), stream);

    fold_kernel<<<517, 256, 0, stream>>>(
        (const float*)d_in[1],  (const float*)d_in[2],  (const float*)d_in[3],  (const float*)d_in[4],  (const float*)d_in[5],  (const float*)d_in[6],
        (const float*)d_in[7],  (const float*)d_in[8],  (const float*)d_in[9],  (const float*)d_in[10], (const float*)d_in[11], (const float*)d_in[12],
        (const float*)d_in[13], (const float*)d_in[14], (const float*)d_in[15], (const float*)d_in[16], (const float*)d_in[17], (const float*)d_in[18],
        (const float*)d_in[19], (const float*)d_in[20], (const float*)d_in[21], (const float*)d_in[22], (const float*)d_in[23], (const float*)d_in[24],
        (const float*)d_in[25], (const float*)d_in[26], (const float*)d_in[27], (const float*)d_in[28], (const float*)d_in[29], (const float*)d_in[30],
        (const float*)d_in[31], (const float*)d_in[32], (const float*)d_in[33], (const float*)d_in[34], (const float*)d_in[35], (const float*)d_in[36],
        (const float*)d_in[37], (const float*)d_in[38], (const float*)d_in[39], (const float*)d_in[40], (const float*)d_in[41], (const float*)d_in[42],
        (const float*)d_in[43], (const float*)d_in[44],
        ws);

    point_mlp_kernel<<<8192, 256, 0, stream>>>(pts, ws);
    knn_kernel<<<512, 512, 0, stream>>>(ws);
    nbr_mlp_mfma_kernel<<<8192, 256, 0, stream>>>(ws);
    gf_kernel<<<dim3(8, 32), 128, 0, stream>>>(ws);
    head_mfma_kernel<<<512, 256, 0, stream>>>(ws, out);
}

// Round 5
// 429.786 us; speedup vs baseline: 1.9716x; 1.1030x over previous
//
#include <hip/hip_runtime.h>
#include <math.h>

// ============================================================================
// Round 5: knn selection phases parallelized — bitonic sorts across 64 lanes,
// all 8 waves participate (was: single-wave serial scans). Dist passes keep
// wave-uniform scalar loads. Everything else unchanged (verified 2.44e-4).
// ============================================================================

#define EPSBN 1e-5f

typedef _Float16 v8h  __attribute__((ext_vector_type(8)));
typedef _Float16 v4h  __attribute__((ext_vector_type(4)));
typedef float    v16f __attribute__((ext_vector_type(16)));

// ---- ws layout (float offsets) ----
#define W0T_OFF   0         // [3][64]
#define B0_OFF    192
#define W1T_OFF   256       // [64][64]
#define B1_OFF    4352
#define A0XT_OFF  4416      // [3][64]
#define A0FT_OFF  4608      // [64][64]
#define BA0_OFF   8704
#define A1T_OFF   8768      // fp16 image [128][64]h swizzled (8192 halfs)
#define BA1_OFF   16960
#define A2T_OFF   17088     // fp16 image [128][128]h swizzled (16384 halfs)
#define BA2_OFF   33472
#define C2T_OFF   33600     // fp16 frag-linear c2 image: 8192 float4 (65536 h)
#define C3H_OFF   66368     // fp16 frag-linear c3 image: 4096 float4 (32768 h)
#define BC2_OFF   99136
#define BC3_OFF   132160
#define C4T_OFF   132288    // [128][6] fp32
#define BC4_OFF   133056
#define PTS4_OFF  133120    // [32768] float4 {x,y,z,sq}
#define Q_OFF     264192    // [32768][64]
#define C_OFF     2361344   // [32768][64]
#define IDX_OFF   4458496   // [32768][16] int (batch-local m)
#define LOCAL_OFF 4982784   // [32768][128]
#define GF_OFF    9177088   // [8][128]

// ---------------------------------------------------------------------------
// Kernel 0: fold BN into weights.
// ---------------------------------------------------------------------------
__device__ __forceinline__ void fold_one(int e, const float* w, const float* b,
    const float* g, const float* t, const float* m, const float* v,
    float* wt, float* bo, int O, int Cfull, int cbeg)
{
    int o = e % O, c = e / O;
    float s = 1.0f;
    if (g) s = g[o] * (1.0f / sqrtf(v[o] + EPSBN));
    wt[c * O + o] = w[o * Cfull + cbeg + c] * s;
    if (c == 0 && bo) {
        float bias = b[o];
        if (g) bias = (bias - m[o]) * s + t[o];
        bo[o] = bias;
    }
}

__global__ __launch_bounds__(256) void fold_kernel(
    const float* c0w, const float* c0b, const float* c0g, const float* c0t, const float* c0m, const float* c0v,
    const float* c1w, const float* c1b, const float* c1g, const float* c1t, const float* c1m, const float* c1v,
    const float* a0w, const float* a0b, const float* a0g, const float* a0t, const float* a0m, const float* a0v,
    const float* a1w, const float* a1b, const float* a1g, const float* a1t, const float* a1m, const float* a1v,
    const float* a2w, const float* a2b, const float* a2g, const float* a2t, const float* a2m, const float* a2v,
    const float* c2w, const float* c2b, const float* c2g, const float* c2t, const float* c2m, const float* c2v,
    const float* c3w, const float* c3b, const float* c3g, const float* c3t, const float* c3m, const float* c3v,
    const float* c4w, const float* c4b,
    float* ws)
{
    int e = blockIdx.x * 256 + threadIdx.x;
    if (e < 192)        { fold_one(e,          c0w, c0b, c0g, c0t, c0m, c0v, ws + W0T_OFF,  ws + B0_OFF,  64, 3,   0); return; }
    e -= 192;
    if (e < 4096)       { fold_one(e,          c1w, c1b, c1g, c1t, c1m, c1v, ws + W1T_OFF,  ws + B1_OFF,  64, 64,  0); return; }
    e -= 4096;
    if (e < 192)        { fold_one(e,          a0w, a0b, a0g, a0t, a0m, a0v, ws + A0XT_OFF, ws + BA0_OFF, 64, 67,  0); return; }
    e -= 192;
    if (e < 4096)       { fold_one(e,          a0w, a0b, a0g, a0t, a0m, a0v, ws + A0FT_OFF, nullptr,      64, 67,  3); return; }
    e -= 4096;
    if (e < 8192) {
        int o = e & 127, c = e >> 7;
        float s = a1g[o] * (1.0f / sqrtf(a1v[o] + EPSBN));
        float val = a1w[o * 64 + c] * s;
        ((_Float16*)(ws + A1T_OFF))[o * 64 + (((c >> 3) ^ (o & 7)) * 8) + (c & 7)] = (_Float16)val;
        if (c == 0) ws[BA1_OFF + o] = (a1b[o] - a1m[o]) * s + a1t[o];
        return;
    }
    e -= 8192;
    if (e < 16384) {
        int o = e & 127, c = e >> 7;
        float s = a2g[o] * (1.0f / sqrtf(a2v[o] + EPSBN));
        float val = a2w[o * 128 + c] * s;
        ((_Float16*)(ws + A2T_OFF))[o * 128 + (((c >> 3) ^ (o & 7)) * 8) + (c & 7)] = (_Float16)val;
        if (c == 0) ws[BA2_OFF + o] = (a2b[o] - a2m[o]) * s + a2t[o];
        return;
    }
    e -= 16384;
    if (e < 65536) {
        int j = e & 7, l = (e >> 3) & 63, s5 = (e >> 9) & 15, ot = e >> 13;
        int o = ot * 32 + (l & 31);
        int c = s5 * 16 + (l >> 5) * 8 + j;
        float sc = c2g[o] * (1.0f / sqrtf(c2v[o] + EPSBN));
        ((_Float16*)(ws + C2T_OFF))[e] = (_Float16)(c2w[o * 256 + c] * sc);
        if (c == 0) ws[BC2_OFF + o] = (c2b[o] - c2m[o]) * sc + c2t[o];
        return;
    }
    e -= 65536;
    if (e < 32768) {
        int j = e & 7, l = (e >> 3) & 63, s5 = (e >> 9) & 15, ot = e >> 13;
        int o = ot * 32 + (l & 31);
        int c = s5 * 16 + (l >> 5) * 8 + j;
        float sc = c3g[o] * (1.0f / sqrtf(c3v[o] + EPSBN));
        ((_Float16*)(ws + C3H_OFF))[e] = (_Float16)(c3w[o * 256 + c] * sc);
        if (c == 0) ws[BC3_OFF + o] = (c3b[o] - c3m[o]) * sc + c3t[o];
        return;
    }
    e -= 32768;
    if (e < 768)        { fold_one(e,          c4w, c4b, nullptr, nullptr, nullptr, nullptr, ws + C4T_OFF, ws + BC4_OFF, 6, 128, 0); return; }
}

// ---------------------------------------------------------------------------
// Kernel 1: per-point MLP 3->64->64 (+ pts4 with exact sq, + q/c for a0 trick)
// ---------------------------------------------------------------------------
__global__ __launch_bounds__(256) void point_mlp_kernel(const float* __restrict__ pts, float* __restrict__ ws)
{
    __shared__ float sh[4][64];
    __shared__ float sx[4][64];
    int lane = threadIdx.x & 63;
    int wv = threadIdx.x >> 6;
    int pid = blockIdx.x * 4 + wv;
    const float* p = pts + pid * 3;
    float x = p[0], y = p[1], z = p[2];
    if (lane == 0) {
        float sq = __fadd_rn(__fadd_rn(__fmul_rn(x, x), __fmul_rn(y, y)), __fmul_rn(z, z));
        ((float4*)(ws + PTS4_OFF))[pid] = make_float4(x, y, z, sq);
    }
    const float* W0T  = ws + W0T_OFF;
    const float* B0   = ws + B0_OFF;
    const float* W1T  = ws + W1T_OFF;
    const float* B1   = ws + B1_OFF;
    const float* A0XT = ws + A0XT_OFF;
    const float* A0FT = ws + A0FT_OFF;
    const float* BA0  = ws + BA0_OFF;

    float h0 = B0[lane];
    h0 = fmaf(x, W0T[lane], h0);
    h0 = fmaf(y, W0T[64 + lane], h0);
    h0 = fmaf(z, W0T[128 + lane], h0);
    h0 = fmaxf(h0, 0.0f);
    sh[wv][lane] = h0;
    __syncthreads();

    float acc = B1[lane];
    #pragma unroll 8
    for (int c = 0; c < 64; ++c) acc = fmaf(W1T[c * 64 + lane], sh[wv][c], acc);
    float x1 = fmaxf(acc, 0.0f);
    sx[wv][lane] = x1;

    float q = __fmul_rn(x, A0XT[lane]);
    q = fmaf(y, A0XT[64 + lane], q);
    q = fmaf(z, A0XT[128 + lane], q);
    ws[Q_OFF + pid * 64 + lane] = q;
    __syncthreads();

    float cacc = q + BA0[lane];
    #pragma unroll 8
    for (int c = 0; c < 64; ++c) cacc = fmaf(A0FT[c * 64 + lane], sx[wv][c], cacc);
    ws[C_OFF + pid * 64 + lane] = cacc;
}

// ---------------------------------------------------------------------------
// Kernel 2: exact kNN. Dist passes: wave-uniform scalar candidate loads.
// Selection: 64-lane bitonic sorts, all 8 waves each handling 8 rows.
// tau = 17th smallest of 64 group minima (guaranteed >= d_(16)).
// Extraction: uint64 key = sortable(d) || idx  -> exact lexicographic order.
// ---------------------------------------------------------------------------
__device__ __forceinline__ float dist2_ref(float xn, float yn, float zn, float sqn, float4 pm)
{
    float dot = __fmul_rn(xn, pm.x);
    dot = __fmaf_rn(yn, pm.y, dot);
    dot = __fmaf_rn(zn, pm.z, dot);
    float s = __fadd_rn(sqn, pm.w);
    return __fsub_rn(s, __fmul_rn(2.0f, dot));
}

#define KNN_CAP 64
__global__ __launch_bounds__(512) void knn_kernel(float* __restrict__ ws)
{
    __shared__ float gmins[64 * 65];          // 16.6KB
    __shared__ float bufd[64 * 65];           // 16.6KB  [row][slot]
    __shared__ int   bufi[64 * 65];           // 16.6KB
    __shared__ int   cnt[64];
    __shared__ float tau[64];

    const float4* __restrict__ pts4 = (const float4*)(ws + PTS4_OFF);
    int* IDX = (int*)(ws + IDX_OFF);

    const int l    = threadIdx.x & 63;        // lane = row in dist passes
    const int row  = l;
    const int wvu  = __builtin_amdgcn_readfirstlane(threadIdx.x >> 6);
    const int base = (blockIdx.x >> 6) << 12;
    const int r    = blockIdx.x * 64 + row;

    if (threadIdx.x < 64) cnt[threadIdx.x] = 0;

    float4 pn = pts4[r];
    float xn = pn.x, yn = pn.y, zn = pn.z, sqn = pn.w;

    // Pass A: 8 groups of 64 candidates per wave, 4 interleaved accumulators.
    #pragma unroll
    for (int g = 0; g < 8; ++g) {
        const float4* __restrict__ cp = pts4 + base + wvu * 512 + g * 64;
        float mn0 = INFINITY, mn1 = INFINITY, mn2 = INFINITY, mn3 = INFINITY;
        #pragma unroll 4
        for (int i = 0; i < 64; i += 4) {
            mn0 = fminf(mn0, dist2_ref(xn, yn, zn, sqn, cp[i + 0]));
            mn1 = fminf(mn1, dist2_ref(xn, yn, zn, sqn, cp[i + 1]));
            mn2 = fminf(mn2, dist2_ref(xn, yn, zn, sqn, cp[i + 2]));
            mn3 = fminf(mn3, dist2_ref(xn, yn, zn, sqn, cp[i + 3]));
        }
        gmins[row * 65 + wvu * 8 + g] = fminf(fminf(mn0, mn1), fminf(mn2, mn3));
    }
    __syncthreads();

    // tau phase: wave wvu sorts rows {8*wvu .. 8*wvu+7}; bitonic across lanes.
    for (int rr = 0; rr < 8; ++rr) {
        int rw = wvu * 8 + rr;
        float v = gmins[rw * 65 + l];
        #pragma unroll
        for (int k = 2; k <= 64; k <<= 1) {
            #pragma unroll
            for (int j = k >> 1; j > 0; j >>= 1) {
                float o = __shfl_xor(v, j);
                bool mx = (((l & j) != 0) == ((l & k) == 0));
                v = mx ? fmaxf(v, o) : fminf(v, o);
            }
        }
        if (l == 16) tau[rw] = v;   // rank 16 (0-indexed) = 17th smallest
    }
    __syncthreads();

    // Pass B: filter by tau, append (d, local m) to per-row buffer
    {
        float tv = tau[row];
        const float4* __restrict__ cp = pts4 + base + wvu * 512;
        #pragma unroll 4
        for (int i = 0; i < 512; ++i) {
            float d = dist2_ref(xn, yn, zn, sqn, cp[i]);
            if (d <= tv) {
                int slot = atomicAdd(&cnt[row], 1);
                if (slot < KNN_CAP) {
                    bufd[row * 65 + slot] = d;
                    bufi[row * 65 + slot] = wvu * 512 + i;
                }
            }
        }
    }
    __syncthreads();

    // Extraction: per row, bitonic-sort up to 64 (d,idx) keys across lanes;
    // lanes 0..15 emit the top-16 in exact lexicographic (d, idx) order.
    for (int rr = 0; rr < 8; ++rr) {
        int rw = wvu * 8 + rr;
        int s = cnt[rw];
        if (s <= KNN_CAP) {
            unsigned long long key = ~0ULL;
            if (l < s) {
                unsigned u = __float_as_uint(bufd[rw * 65 + l]);
                u = (u & 0x80000000u) ? ~u : (u | 0x80000000u);
                key = ((unsigned long long)u << 32) | (unsigned)bufi[rw * 65 + l];
            }
            #pragma unroll
            for (int k = 2; k <= 64; k <<= 1) {
                #pragma unroll
                for (int j = k >> 1; j > 0; j >>= 1) {
                    unsigned long long o = __shfl_xor(key, j);
                    bool mx = (((l & j) != 0) == ((l & k) == 0));
                    key = mx ? (key > o ? key : o) : (key < o ? key : o);
                }
            }
            if (l < 16)
                IDX[(blockIdx.x * 64 + rw) * 16 + l] = (int)(key & 0xFFFFFFFFu);
        }
    }

    // overflow fallback (practically never): exact serial top-16
    if (threadIdx.x < 64 && cnt[threadIdx.x] > KNN_CAP) {
        int* out = IDX + (blockIdx.x * 64 + threadIdx.x) * 16;
        float hd[16]; int hi[16];
        #pragma unroll
        for (int t2 = 0; t2 < 16; ++t2) { hd[t2] = INFINITY; hi[t2] = 0; }
        for (int mm = 0; mm < 4096; ++mm) {
            float d = dist2_ref(xn, yn, zn, sqn, pts4[base + mm]);
            if (d < hd[15]) {
                float vd = d; int vi = mm;
                #pragma unroll
                for (int t2 = 0; t2 < 16; ++t2) {
                    bool sm = vd < hd[t2];
                    float td = hd[t2]; int ti = hi[t2];
                    if (sm) { hd[t2] = vd; hi[t2] = vi; vd = td; vi = ti; }
                }
            }
        }
        for (int jj = 0; jj < 16; ++jj) out[jj] = hi[jj];
    }
}

// ---------------------------------------------------------------------------
// Kernel 3: a1+a2 fp16 MFMA (unchanged — verified).
// ---------------------------------------------------------------------------
__global__ __launch_bounds__(256) void nbr_mlp_mfma_kernel(float* __restrict__ ws)
{
    __shared__ __align__(16) _Float16 sH1[64 * 128];
    __shared__ __align__(16) _Float16 sWG[16384];
    _Float16* sW1 = sWG;
    _Float16* sG1 = sWG + 8192;
    _Float16* sW2 = sWG;

    const int t   = threadIdx.x;
    const int l   = t & 63;
    const int w   = t >> 6;
    const int ln  = l & 31;
    const int hi  = l >> 5;
    const int blk = blockIdx.x;
    const int gpt0 = blk * 4;
    const int base = (blk >> 10) << 12;

    const float* Cf = ws + C_OFF;
    const float* Qf = ws + Q_OFF;
    const int* IDX = (const int*)(ws + IDX_OFF);
    const float4* w1img = (const float4*)(ws + A1T_OFF);
    const float4* w2img = (const float4*)(ws + A2T_OFF);

    float4 w2r[8];
    #pragma unroll
    for (int u = 0; u < 8; ++u) w2r[u] = w2img[t + 256 * u];

    {
        float4* d = (float4*)sW1;
        #pragma unroll
        for (int u = 0; u < 4; ++u) d[t + 256 * u] = w1img[t + 256 * u];
    }
    {
        int r = t >> 2, cs = t & 3;
        int gpt = gpt0 + (r >> 4);
        int m = IDX[gpt * 16 + (r & 15)];
        const float4* crow = (const float4*)(Cf + (size_t)(base + m) * 64) + cs * 4;
        const float4* qrow = (const float4*)(Qf + (size_t)gpt * 64) + cs * 4;
        v8h h0, h1;
        #pragma unroll
        for (int u = 0; u < 2; ++u) {
            float4 cv = crow[u], qv = qrow[u];
            h0[u * 4 + 0] = (_Float16)fmaxf(cv.x - qv.x, 0.0f);
            h0[u * 4 + 1] = (_Float16)fmaxf(cv.y - qv.y, 0.0f);
            h0[u * 4 + 2] = (_Float16)fmaxf(cv.z - qv.z, 0.0f);
            h0[u * 4 + 3] = (_Float16)fmaxf(cv.w - qv.w, 0.0f);
        }
        #pragma unroll
        for (int u = 0; u < 2; ++u) {
            float4 cv = crow[2 + u], qv = qrow[2 + u];
            h1[u * 4 + 0] = (_Float16)fmaxf(cv.x - qv.x, 0.0f);
            h1[u * 4 + 1] = (_Float16)fmaxf(cv.y - qv.y, 0.0f);
            h1[u * 4 + 2] = (_Float16)fmaxf(cv.z - qv.z, 0.0f);
            h1[u * 4 + 3] = (_Float16)fmaxf(cv.w - qv.w, 0.0f);
        }
        int rs = r & 7;
        *(v8h*)&sG1[r * 64 + ((cs * 2    ) ^ rs) * 8] = h0;
        *(v8h*)&sG1[r * 64 + ((cs * 2 + 1) ^ rs) * 8] = h1;
    }
    float bias1[16], bias2[16];
    #pragma unroll
    for (int i = 0; i < 16; ++i) {
        int ob = w * 32 + (i & 3) + 8 * (i >> 2) + 4 * hi;
        bias1[i] = ws[BA1_OFF + ob];
        bias2[i] = ws[BA2_OFF + ob];
    }
    __syncthreads();

    v8h fa[4];
    {
        int o = w * 32 + ln, os = o & 7;
        #pragma unroll
        for (int kf = 0; kf < 4; ++kf)
            fa[kf] = *(const v8h*)&sW1[o * 64 + ((kf * 2 + hi) ^ os) * 8];
    }
    #pragma unroll
    for (int rt = 0; rt < 2; ++rt) {
        int r = rt * 32 + ln, rs = r & 7;
        v16f acc;
        #pragma unroll
        for (int i = 0; i < 16; ++i) acc[i] = 0.0f;
        #pragma unroll
        for (int kf = 0; kf < 4; ++kf) {
            v8h fb = *(const v8h*)&sG1[r * 64 + ((kf * 2 + hi) ^ rs) * 8];
            acc = __builtin_amdgcn_mfma_f32_32x32x16_f16(fa[kf], fb, acc, 0, 0, 0);
        }
        #pragma unroll
        for (int q = 0; q < 4; ++q) {
            v4h hv;
            #pragma unroll
            for (int j = 0; j < 4; ++j)
                hv[j] = (_Float16)fmaxf(acc[q * 4 + j] + bias1[q * 4 + j], 0.0f);
            int g = w * 4 + q;
            *(v4h*)&sH1[r * 128 + ((g ^ rs) * 8) + 4 * hi] = hv;
        }
    }
    __syncthreads();
    {
        float4* d = (float4*)sW2;
        #pragma unroll
        for (int u = 0; u < 8; ++u) d[t + 256 * u] = w2r[u];
    }
    __syncthreads();

    v8h fa2[8];
    {
        int o = w * 32 + ln, os = o & 7;
        #pragma unroll
        for (int kf = 0; kf < 8; ++kf)
            fa2[kf] = *(const v8h*)&sW2[o * 128 + ((kf * 2 + hi) ^ os) * 8];
    }
    float* LOCAL = ws + LOCAL_OFF;
    #pragma unroll
    for (int rt = 0; rt < 2; ++rt) {
        int r = rt * 32 + ln, rs = r & 7;
        v16f acc;
        #pragma unroll
        for (int i = 0; i < 16; ++i) acc[i] = 0.0f;
        #pragma unroll
        for (int kf = 0; kf < 8; ++kf) {
            v8h fb = *(const v8h*)&sH1[r * 128 + ((kf * 2 + hi) ^ rs) * 8];
            acc = __builtin_amdgcn_mfma_f32_32x32x16_f16(fa2[kf], fb, acc, 0, 0, 0);
        }
        #pragma unroll
        for (int i = 0; i < 16; ++i) {
            float v = acc[i];
            v = fmaxf(v, __shfl_xor(v, 1));
            v = fmaxf(v, __shfl_xor(v, 2));
            v = fmaxf(v, __shfl_xor(v, 4));
            v = fmaxf(v, __shfl_xor(v, 8));
            acc[i] = v;
        }
        if ((l & 15) == 0) {
            int p = gpt0 + rt * 2 + ((l >> 4) & 1);
            #pragma unroll
            for (int q = 0; q < 4; ++q) {
                float4 o4;
                o4.x = fmaxf(acc[q * 4 + 0] + bias2[q * 4 + 0], 0.0f);
                o4.y = fmaxf(acc[q * 4 + 1] + bias2[q * 4 + 1], 0.0f);
                o4.z = fmaxf(acc[q * 4 + 2] + bias2[q * 4 + 2], 0.0f);
                o4.w = fmaxf(acc[q * 4 + 3] + bias2[q * 4 + 3], 0.0f);
                int ob = w * 32 + 8 * q + 4 * hi;
                *(float4*)&LOCAL[(size_t)p * 128 + ob] = o4;
            }
        }
    }
}

// ---------------------------------------------------------------------------
// Kernel 4: global feature = max over N of local.
// ---------------------------------------------------------------------------
__global__ __launch_bounds__(128) void gf_kernel(float* __restrict__ ws)
{
    int b = blockIdx.x, sl = blockIdx.y;
    int c = threadIdx.x;
    const float* LOCAL = ws + LOCAL_OFF + (size_t)(b * 4096 + sl * 128) * 128;
    float m = 0.0f;
    #pragma unroll 4
    for (int i = 0; i < 128; ++i) m = fmaxf(m, LOCAL[i * 128 + c]);
    atomicMax((int*)(ws + GF_OFF) + b * 128 + c, __float_as_int(m));
}

// ---------------------------------------------------------------------------
// Kernel 5: head c2/c3 fp16 MFMA + c4 fp32 (unchanged — verified).
// ---------------------------------------------------------------------------
__global__ __launch_bounds__(256) void head_mfma_kernel(float* __restrict__ ws, float* __restrict__ out)
{
    __shared__ __align__(16) unsigned char smem[66560];
    _Float16* sF  = (_Float16*)smem;
    float*    sF3 = (float*)smem;
    _Float16* sF2 = (_Float16*)(smem + 33792);

    const int t  = threadIdx.x;
    const int l  = t & 63;
    const int w  = t >> 6;
    const int ln = l & 31;
    const int hi = l >> 5;
    const int gpt0 = blockIdx.x * 64;
    const int b = blockIdx.x >> 6;

    const float4* c2h = (const float4*)(ws + C2T_OFF);
    const float4* c3h = (const float4*)(ws + C3H_OFF);

    {
        int m = t >> 2, cs = t & 3;
        const float4* src = (cs < 2)
            ? (const float4*)(ws + LOCAL_OFF + (size_t)(gpt0 + m) * 128) + cs * 16
            : (const float4*)(ws + GF_OFF + b * 128) + (cs - 2) * 16;
        int c0 = cs * 64;
        #pragma unroll
        for (int u = 0; u < 8; ++u) {
            float4 a0 = src[u * 2], a1 = src[u * 2 + 1];
            v8h h;
            h[0] = (_Float16)a0.x; h[1] = (_Float16)a0.y;
            h[2] = (_Float16)a0.z; h[3] = (_Float16)a0.w;
            h[4] = (_Float16)a1.x; h[5] = (_Float16)a1.y;
            h[6] = (_Float16)a1.z; h[7] = (_Float16)a1.w;
            int g = ((c0 >> 3) + u) ^ (m & 31);
            *(v8h*)&sF[m * 256 + g * 8] = h;
        }
    }
    __syncthreads();

    #pragma unroll
    for (int ot = 0; ot < 2; ++ot) {
        int ot2 = 2 * w + ot;
        v8h fa[16];
        #pragma unroll
        for (int s = 0; s < 16; ++s) {
            float4 tmp = c2h[(ot2 * 16 + s) * 64 + l];
            fa[s] = *(v8h*)&tmp;
        }
        float b2[16];
        #pragma unroll
        for (int i = 0; i < 16; ++i)
            b2[i] = ws[BC2_OFF + ot2 * 32 + (i & 3) + 8 * (i >> 2) + 4 * hi];
        #pragma unroll
        for (int mt = 0; mt < 2; ++mt) {
            int m = mt * 32 + ln;
            v16f acc;
            #pragma unroll
            for (int i = 0; i < 16; ++i) acc[i] = 0.0f;
            #pragma unroll
            for (int s = 0; s < 16; ++s) {
                v8h fb = *(const v8h*)&sF[m * 256 + (((2 * s + hi) ^ ln) * 8)];
                acc = __builtin_amdgcn_mfma_f32_32x32x16_f16(fa[s], fb, acc, 0, 0, 0);
            }
            #pragma unroll
            for (int q = 0; q < 4; ++q) {
                v4h hv;
                #pragma unroll
                for (int j = 0; j < 4; ++j)
                    hv[j] = (_Float16)fmaxf(acc[q * 4 + j] + b2[q * 4 + j], 0.0f);
                *(v4h*)&sF2[m * 256 + (((ot2 * 4 + q) ^ ln) * 8) + 4 * hi] = hv;
            }
        }
    }
    __syncthreads();

    {
        v8h fa[16];
        #pragma unroll
        for (int s = 0; s < 16; ++s) {
            float4 tmp = c3h[(w * 16 + s) * 64 + l];
            fa[s] = *(v8h*)&tmp;
        }
        float b3[16];
        #pragma unroll
        for (int i = 0; i < 16; ++i)
            b3[i] = ws[BC3_OFF + w * 32 + (i & 3) + 8 * (i >> 2) + 4 * hi];
        #pragma unroll
        for (int mt = 0; mt < 2; ++mt) {
            int m = mt * 32 + ln;
            v16f acc;
            #pragma unroll
            for (int i = 0; i < 16; ++i) acc[i] = 0.0f;
            #pragma unroll
            for (int s = 0; s < 16; ++s) {
                v8h fb = *(const v8h*)&sF2[m * 256 + (((2 * s + hi) ^ ln) * 8)];
                acc = __builtin_amdgcn_mfma_f32_32x32x16_f16(fa[s], fb, acc, 0, 0, 0);
            }
            #pragma unroll
            for (int q = 0; q < 4; ++q) {
                float4 hv;
                hv.x = fmaxf(acc[q * 4 + 0] + b3[q * 4 + 0], 0.0f);
                hv.y = fmaxf(acc[q * 4 + 1] + b3[q * 4 + 1], 0.0f);
                hv.z = fmaxf(acc[q * 4 + 2] + b3[q * 4 + 2], 0.0f);
                hv.w = fmaxf(acc[q * 4 + 3] + b3[q * 4 + 3], 0.0f);
                *(float4*)&sF3[m * 132 + w * 32 + q * 8 + 4 * hi] = hv;
            }
        }
    }
    __syncthreads();

    const float* C4T = ws + C4T_OFF;
    for (int mo = t; mo < 384; mo += 256) {
        int m = mo / 6, o = mo - m * 6;
        float a = ws[BC4_OFF + o];
        const float4* f4 = (const float4*)(sF3 + m * 132);
        #pragma unroll 8
        for (int kq = 0; kq < 32; ++kq) {
            float4 f = f4[kq];
            a = fmaf(f.x, C4T[(kq * 4 + 0) * 6 + o], a);
            a = fmaf(f.y, C4T[(kq * 4 + 1) * 6 + o], a);
            a = fmaf(f.z, C4T[(kq * 4 + 2) * 6 + o], a);
            a = fmaf(f.w, C4T[(kq * 4 + 3) * 6 + o], a);
        }
        out[(size_t)(gpt0 + m) * 6 + o] = a;
    }
}

// ---------------------------------------------------------------------------
extern "C" void kernel_launch(void* const* d_in, const int* in_sizes, int n_in,
                              void* d_out, int out_size, void* d_ws, size_t ws_size,
                              hipStream_t stream)
{
    const float* pts = (const float*)d_in[0];
    float* ws = (float*)d_ws;
    float* out = (float*)d_out;

    hipMemsetAsync(ws + GF_OFF, 0, 1024 * sizeof(float), stream);

    fold_kernel<<<517, 256, 0, stream>>>(
        (const float*)d_in[1],  (const float*)d_in[2],  (const float*)d_in[3],  (const float*)d_in[4],  (const float*)d_in[5],  (const float*)d_in[6],
        (const float*)d_in[7],  (const float*)d_in[8],  (const float*)d_in[9],  (const float*)d_in[10], (const float*)d_in[11], (const float*)d_in[12],
        (const float*)d_in[13], (const float*)d_in[14], (const float*)d_in[15], (const float*)d_in[16], (const float*)d_in[17], (const float*)d_in[18],
        (const float*)d_in[19], (const float*)d_in[20], (const float*)d_in[21], (const float*)d_in[22], (const float*)d_in[23], (const float*)d_in[24],
        (const float*)d_in[25], (const float*)d_in[26], (const float*)d_in[27], (const float*)d_in[28], (const float*)d_in[29], (const float*)d_in[30],
        (const float*)d_in[31], (const float*)d_in[32], (const float*)d_in[33], (const float*)d_in[34], (const float*)d_in[35], (const float*)d_in[36],
        (const float*)d_in[37], (const float*)d_in[38], (const float*)d_in[39], (const float*)d_in[40], (const float*)d_in[41], (const float*)d_in[42],
        (const float*)d_in[43], (const float*)d_in[44],
        ws);

    point_mlp_kernel<<<8192, 256, 0, stream>>>(pts, ws);
    knn_kernel<<<512, 512, 0, stream>>>(ws);
    nbr_mlp_mfma_kernel<<<8192, 256, 0, stream>>>(ws);
    gf_kernel<<<dim3(8, 32), 128, 0, stream>>>(ws);
    head_mfma_kernel<<<512, 256, 0, stream>>>(ws, out);
}

// Round 6
// 405.489 us; speedup vs baseline: 2.0897x; 1.0599x over previous
//
#include <hip/hip_runtime.h>
#include <math.h>

// ============================================================================
// Round 6: nbr_mlp v2 — 16 points/block, weights staged to LDS ONCE per block
// (was: 48KB re-staged per 4 points = 393MB L2 thrash), pooled output written
// via fully-coalesced burst (was: 4-lane sparse stores -> 278MB write ampl.).
// Everything else unchanged from Round 5 (verified, absmax 2.44e-4).
// ============================================================================

#define EPSBN 1e-5f

typedef _Float16 v8h  __attribute__((ext_vector_type(8)));
typedef _Float16 v4h  __attribute__((ext_vector_type(4)));
typedef float    v16f __attribute__((ext_vector_type(16)));

// ---- ws layout (float offsets) ----
#define W0T_OFF   0         // [3][64]
#define B0_OFF    192
#define W1T_OFF   256       // [64][64]
#define B1_OFF    4352
#define A0XT_OFF  4416      // [3][64]
#define A0FT_OFF  4608      // [64][64]
#define BA0_OFF   8704
#define A1T_OFF   8768      // fp16 image [128][64]h swizzled (8192 halfs)
#define BA1_OFF   16960
#define A2T_OFF   17088     // fp16 image [128][128]h swizzled (16384 halfs)
#define BA2_OFF   33472
#define C2T_OFF   33600     // fp16 frag-linear c2 image: 8192 float4 (65536 h)
#define C3H_OFF   66368     // fp16 frag-linear c3 image: 4096 float4 (32768 h)
#define BC2_OFF   99136
#define BC3_OFF   132160
#define C4T_OFF   132288    // [128][6] fp32
#define BC4_OFF   133056
#define PTS4_OFF  133120    // [32768] float4 {x,y,z,sq}
#define Q_OFF     264192    // [32768][64]
#define C_OFF     2361344   // [32768][64]
#define IDX_OFF   4458496   // [32768][16] int (batch-local m)
#define LOCAL_OFF 4982784   // [32768][128]
#define GF_OFF    9177088   // [8][128]

// ---------------------------------------------------------------------------
// Kernel 0: fold BN into weights.
// ---------------------------------------------------------------------------
__device__ __forceinline__ void fold_one(int e, const float* w, const float* b,
    const float* g, const float* t, const float* m, const float* v,
    float* wt, float* bo, int O, int Cfull, int cbeg)
{
    int o = e % O, c = e / O;
    float s = 1.0f;
    if (g) s = g[o] * (1.0f / sqrtf(v[o] + EPSBN));
    wt[c * O + o] = w[o * Cfull + cbeg + c] * s;
    if (c == 0 && bo) {
        float bias = b[o];
        if (g) bias = (bias - m[o]) * s + t[o];
        bo[o] = bias;
    }
}

__global__ __launch_bounds__(256) void fold_kernel(
    const float* c0w, const float* c0b, const float* c0g, const float* c0t, const float* c0m, const float* c0v,
    const float* c1w, const float* c1b, const float* c1g, const float* c1t, const float* c1m, const float* c1v,
    const float* a0w, const float* a0b, const float* a0g, const float* a0t, const float* a0m, const float* a0v,
    const float* a1w, const float* a1b, const float* a1g, const float* a1t, const float* a1m, const float* a1v,
    const float* a2w, const float* a2b, const float* a2g, const float* a2t, const float* a2m, const float* a2v,
    const float* c2w, const float* c2b, const float* c2g, const float* c2t, const float* c2m, const float* c2v,
    const float* c3w, const float* c3b, const float* c3g, const float* c3t, const float* c3m, const float* c3v,
    const float* c4w, const float* c4b,
    float* ws)
{
    int e = blockIdx.x * 256 + threadIdx.x;
    if (e < 192)        { fold_one(e,          c0w, c0b, c0g, c0t, c0m, c0v, ws + W0T_OFF,  ws + B0_OFF,  64, 3,   0); return; }
    e -= 192;
    if (e < 4096)       { fold_one(e,          c1w, c1b, c1g, c1t, c1m, c1v, ws + W1T_OFF,  ws + B1_OFF,  64, 64,  0); return; }
    e -= 4096;
    if (e < 192)        { fold_one(e,          a0w, a0b, a0g, a0t, a0m, a0v, ws + A0XT_OFF, ws + BA0_OFF, 64, 67,  0); return; }
    e -= 192;
    if (e < 4096)       { fold_one(e,          a0w, a0b, a0g, a0t, a0m, a0v, ws + A0FT_OFF, nullptr,      64, 67,  3); return; }
    e -= 4096;
    if (e < 8192) {
        int o = e & 127, c = e >> 7;
        float s = a1g[o] * (1.0f / sqrtf(a1v[o] + EPSBN));
        float val = a1w[o * 64 + c] * s;
        ((_Float16*)(ws + A1T_OFF))[o * 64 + (((c >> 3) ^ (o & 7)) * 8) + (c & 7)] = (_Float16)val;
        if (c == 0) ws[BA1_OFF + o] = (a1b[o] - a1m[o]) * s + a1t[o];
        return;
    }
    e -= 8192;
    if (e < 16384) {
        int o = e & 127, c = e >> 7;
        float s = a2g[o] * (1.0f / sqrtf(a2v[o] + EPSBN));
        float val = a2w[o * 128 + c] * s;
        ((_Float16*)(ws + A2T_OFF))[o * 128 + (((c >> 3) ^ (o & 7)) * 8) + (c & 7)] = (_Float16)val;
        if (c == 0) ws[BA2_OFF + o] = (a2b[o] - a2m[o]) * s + a2t[o];
        return;
    }
    e -= 16384;
    if (e < 65536) {
        int j = e & 7, l = (e >> 3) & 63, s5 = (e >> 9) & 15, ot = e >> 13;
        int o = ot * 32 + (l & 31);
        int c = s5 * 16 + (l >> 5) * 8 + j;
        float sc = c2g[o] * (1.0f / sqrtf(c2v[o] + EPSBN));
        ((_Float16*)(ws + C2T_OFF))[e] = (_Float16)(c2w[o * 256 + c] * sc);
        if (c == 0) ws[BC2_OFF + o] = (c2b[o] - c2m[o]) * sc + c2t[o];
        return;
    }
    e -= 65536;
    if (e < 32768) {
        int j = e & 7, l = (e >> 3) & 63, s5 = (e >> 9) & 15, ot = e >> 13;
        int o = ot * 32 + (l & 31);
        int c = s5 * 16 + (l >> 5) * 8 + j;
        float sc = c3g[o] * (1.0f / sqrtf(c3v[o] + EPSBN));
        ((_Float16*)(ws + C3H_OFF))[e] = (_Float16)(c3w[o * 256 + c] * sc);
        if (c == 0) ws[BC3_OFF + o] = (c3b[o] - c3m[o]) * sc + c3t[o];
        return;
    }
    e -= 32768;
    if (e < 768)        { fold_one(e,          c4w, c4b, nullptr, nullptr, nullptr, nullptr, ws + C4T_OFF, ws + BC4_OFF, 6, 128, 0); return; }
}

// ---------------------------------------------------------------------------
// Kernel 1: per-point MLP 3->64->64 (+ pts4 with exact sq, + q/c for a0 trick)
// ---------------------------------------------------------------------------
__global__ __launch_bounds__(256) void point_mlp_kernel(const float* __restrict__ pts, float* __restrict__ ws)
{
    __shared__ float sh[4][64];
    __shared__ float sx[4][64];
    int lane = threadIdx.x & 63;
    int wv = threadIdx.x >> 6;
    int pid = blockIdx.x * 4 + wv;
    const float* p = pts + pid * 3;
    float x = p[0], y = p[1], z = p[2];
    if (lane == 0) {
        float sq = __fadd_rn(__fadd_rn(__fmul_rn(x, x), __fmul_rn(y, y)), __fmul_rn(z, z));
        ((float4*)(ws + PTS4_OFF))[pid] = make_float4(x, y, z, sq);
    }
    const float* W0T  = ws + W0T_OFF;
    const float* B0   = ws + B0_OFF;
    const float* W1T  = ws + W1T_OFF;
    const float* B1   = ws + B1_OFF;
    const float* A0XT = ws + A0XT_OFF;
    const float* A0FT = ws + A0FT_OFF;
    const float* BA0  = ws + BA0_OFF;

    float h0 = B0[lane];
    h0 = fmaf(x, W0T[lane], h0);
    h0 = fmaf(y, W0T[64 + lane], h0);
    h0 = fmaf(z, W0T[128 + lane], h0);
    h0 = fmaxf(h0, 0.0f);
    sh[wv][lane] = h0;
    __syncthreads();

    float acc = B1[lane];
    #pragma unroll 8
    for (int c = 0; c < 64; ++c) acc = fmaf(W1T[c * 64 + lane], sh[wv][c], acc);
    float x1 = fmaxf(acc, 0.0f);
    sx[wv][lane] = x1;

    float q = __fmul_rn(x, A0XT[lane]);
    q = fmaf(y, A0XT[64 + lane], q);
    q = fmaf(z, A0XT[128 + lane], q);
    ws[Q_OFF + pid * 64 + lane] = q;
    __syncthreads();

    float cacc = q + BA0[lane];
    #pragma unroll 8
    for (int c = 0; c < 64; ++c) cacc = fmaf(A0FT[c * 64 + lane], sx[wv][c], cacc);
    ws[C_OFF + pid * 64 + lane] = cacc;
}

// ---------------------------------------------------------------------------
// Kernel 2: exact kNN (unchanged from Round 5 — verified).
// ---------------------------------------------------------------------------
__device__ __forceinline__ float dist2_ref(float xn, float yn, float zn, float sqn, float4 pm)
{
    float dot = __fmul_rn(xn, pm.x);
    dot = __fmaf_rn(yn, pm.y, dot);
    dot = __fmaf_rn(zn, pm.z, dot);
    float s = __fadd_rn(sqn, pm.w);
    return __fsub_rn(s, __fmul_rn(2.0f, dot));
}

#define KNN_CAP 64
__global__ __launch_bounds__(512) void knn_kernel(float* __restrict__ ws)
{
    __shared__ float gmins[64 * 65];
    __shared__ float bufd[64 * 65];
    __shared__ int   bufi[64 * 65];
    __shared__ int   cnt[64];
    __shared__ float tau[64];

    const float4* __restrict__ pts4 = (const float4*)(ws + PTS4_OFF);
    int* IDX = (int*)(ws + IDX_OFF);

    const int l    = threadIdx.x & 63;
    const int row  = l;
    const int wvu  = __builtin_amdgcn_readfirstlane(threadIdx.x >> 6);
    const int base = (blockIdx.x >> 6) << 12;
    const int r    = blockIdx.x * 64 + row;

    if (threadIdx.x < 64) cnt[threadIdx.x] = 0;

    float4 pn = pts4[r];
    float xn = pn.x, yn = pn.y, zn = pn.z, sqn = pn.w;

    #pragma unroll
    for (int g = 0; g < 8; ++g) {
        const float4* __restrict__ cp = pts4 + base + wvu * 512 + g * 64;
        float mn0 = INFINITY, mn1 = INFINITY, mn2 = INFINITY, mn3 = INFINITY;
        #pragma unroll 4
        for (int i = 0; i < 64; i += 4) {
            mn0 = fminf(mn0, dist2_ref(xn, yn, zn, sqn, cp[i + 0]));
            mn1 = fminf(mn1, dist2_ref(xn, yn, zn, sqn, cp[i + 1]));
            mn2 = fminf(mn2, dist2_ref(xn, yn, zn, sqn, cp[i + 2]));
            mn3 = fminf(mn3, dist2_ref(xn, yn, zn, sqn, cp[i + 3]));
        }
        gmins[row * 65 + wvu * 8 + g] = fminf(fminf(mn0, mn1), fminf(mn2, mn3));
    }
    __syncthreads();

    for (int rr = 0; rr < 8; ++rr) {
        int rw = wvu * 8 + rr;
        float v = gmins[rw * 65 + l];
        #pragma unroll
        for (int k = 2; k <= 64; k <<= 1) {
            #pragma unroll
            for (int j = k >> 1; j > 0; j >>= 1) {
                float o = __shfl_xor(v, j);
                bool mx = (((l & j) != 0) == ((l & k) == 0));
                v = mx ? fmaxf(v, o) : fminf(v, o);
            }
        }
        if (l == 16) tau[rw] = v;
    }
    __syncthreads();

    {
        float tv = tau[row];
        const float4* __restrict__ cp = pts4 + base + wvu * 512;
        #pragma unroll 4
        for (int i = 0; i < 512; ++i) {
            float d = dist2_ref(xn, yn, zn, sqn, cp[i]);
            if (d <= tv) {
                int slot = atomicAdd(&cnt[row], 1);
                if (slot < KNN_CAP) {
                    bufd[row * 65 + slot] = d;
                    bufi[row * 65 + slot] = wvu * 512 + i;
                }
            }
        }
    }
    __syncthreads();

    for (int rr = 0; rr < 8; ++rr) {
        int rw = wvu * 8 + rr;
        int s = cnt[rw];
        if (s <= KNN_CAP) {
            unsigned long long key = ~0ULL;
            if (l < s) {
                unsigned u = __float_as_uint(bufd[rw * 65 + l]);
                u = (u & 0x80000000u) ? ~u : (u | 0x80000000u);
                key = ((unsigned long long)u << 32) | (unsigned)bufi[rw * 65 + l];
            }
            #pragma unroll
            for (int k = 2; k <= 64; k <<= 1) {
                #pragma unroll
                for (int j = k >> 1; j > 0; j >>= 1) {
                    unsigned long long o = __shfl_xor(key, j);
                    bool mx = (((l & j) != 0) == ((l & k) == 0));
                    key = mx ? (key > o ? key : o) : (key < o ? key : o);
                }
            }
            if (l < 16)
                IDX[(blockIdx.x * 64 + rw) * 16 + l] = (int)(key & 0xFFFFFFFFu);
        }
    }

    if (threadIdx.x < 64 && cnt[threadIdx.x] > KNN_CAP) {
        int* out = IDX + (blockIdx.x * 64 + threadIdx.x) * 16;
        float hd[16]; int hi[16];
        #pragma unroll
        for (int t2 = 0; t2 < 16; ++t2) { hd[t2] = INFINITY; hi[t2] = 0; }
        for (int mm = 0; mm < 4096; ++mm) {
            float d = dist2_ref(xn, yn, zn, sqn, pts4[base + mm]);
            if (d < hd[15]) {
                float vd = d; int vi = mm;
                #pragma unroll
                for (int t2 = 0; t2 < 16; ++t2) {
                    bool sm = vd < hd[t2];
                    float td = hd[t2]; int ti = hi[t2];
                    if (sm) { hd[t2] = vd; hi[t2] = vi; vd = td; vi = ti; }
                }
            }
        }
        for (int jj = 0; jj < 16; ++jj) out[jj] = hi[jj];
    }
}

// ---------------------------------------------------------------------------
// Kernel 3 (v2): a1+a2 fp16 MFMA, 16 points/block, weights staged once.
// LDS: sW1 16K | sW2 32K | sG1 8K | sH1 16K | sPool 8K = 80KB -> 2 blocks/CU.
// Loop over 4 groups of 4 points; next group's gather issued alongside a2.
// Final LOCAL write is one coalesced 8KB burst from sPool.
// ---------------------------------------------------------------------------
__device__ __forceinline__ void nbr_stage_g1(
    _Float16* sG1, const float* Cf, const float* Qf, const int* IDX,
    int t, int gpt0, int g, int base)
{
    int r = t >> 2, cs = t & 3;
    int gpt = gpt0 + g * 4 + (r >> 4);
    int m = IDX[gpt * 16 + (r & 15)];
    const float4* crow = (const float4*)(Cf + (size_t)(base + m) * 64) + cs * 4;
    const float4* qrow = (const float4*)(Qf + (size_t)gpt * 64) + cs * 4;
    v8h h0, h1;
    #pragma unroll
    for (int u = 0; u < 2; ++u) {
        float4 cv = crow[u], qv = qrow[u];
        h0[u * 4 + 0] = (_Float16)fmaxf(cv.x - qv.x, 0.0f);
        h0[u * 4 + 1] = (_Float16)fmaxf(cv.y - qv.y, 0.0f);
        h0[u * 4 + 2] = (_Float16)fmaxf(cv.z - qv.z, 0.0f);
        h0[u * 4 + 3] = (_Float16)fmaxf(cv.w - qv.w, 0.0f);
    }
    #pragma unroll
    for (int u = 0; u < 2; ++u) {
        float4 cv = crow[2 + u], qv = qrow[2 + u];
        h1[u * 4 + 0] = (_Float16)fmaxf(cv.x - qv.x, 0.0f);
        h1[u * 4 + 1] = (_Float16)fmaxf(cv.y - qv.y, 0.0f);
        h1[u * 4 + 2] = (_Float16)fmaxf(cv.z - qv.z, 0.0f);
        h1[u * 4 + 3] = (_Float16)fmaxf(cv.w - qv.w, 0.0f);
    }
    int rs = r & 7;
    *(v8h*)&sG1[r * 64 + ((cs * 2    ) ^ rs) * 8] = h0;
    *(v8h*)&sG1[r * 64 + ((cs * 2 + 1) ^ rs) * 8] = h1;
}

__global__ __launch_bounds__(256) void nbr_mlp_mfma_kernel(float* __restrict__ ws)
{
    __shared__ __align__(16) unsigned char smem[81920];
    _Float16* sW1   = (_Float16*)smem;               // [128][64]h swz
    _Float16* sW2   = (_Float16*)(smem + 16384);     // [128][128]h swz
    _Float16* sG1   = (_Float16*)(smem + 49152);     // [64][64]h swz
    _Float16* sH1   = (_Float16*)(smem + 57344);     // [64][128]h swz
    float*    sPool = (float*)(smem + 73728);        // [16][128]f

    const int t   = threadIdx.x;
    const int l   = t & 63;
    const int w   = t >> 6;
    const int ln  = l & 31;
    const int hi  = l >> 5;
    const int blk = blockIdx.x;
    const int gpt0 = blk * 16;
    const int base = (blk >> 8) << 12;

    const float* Cf = ws + C_OFF;
    const float* Qf = ws + Q_OFF;
    const int* IDX = (const int*)(ws + IDX_OFF);

    // stage weights once + first G1
    {
        const float4* w1img = (const float4*)(ws + A1T_OFF);
        const float4* w2img = (const float4*)(ws + A2T_OFF);
        float4* d1 = (float4*)sW1;
        #pragma unroll
        for (int u = 0; u < 4; ++u) d1[t + 256 * u] = w1img[t + 256 * u];
        float4* d2 = (float4*)sW2;
        #pragma unroll
        for (int u = 0; u < 8; ++u) d2[t + 256 * u] = w2img[t + 256 * u];
    }
    nbr_stage_g1(sG1, Cf, Qf, IDX, t, gpt0, 0, base);

    float bias1[16], bias2[16];
    #pragma unroll
    for (int i = 0; i < 16; ++i) {
        int ob = w * 32 + (i & 3) + 8 * (i >> 2) + 4 * hi;
        bias1[i] = ws[BA1_OFF + ob];
        bias2[i] = ws[BA2_OFF + ob];
    }
    __syncthreads();

    // hoisted weight fragments (reused all 4 groups)
    v8h fa[4], fa2[8];
    {
        int o = w * 32 + ln, os = o & 7;
        #pragma unroll
        for (int kf = 0; kf < 4; ++kf)
            fa[kf] = *(const v8h*)&sW1[o * 64 + ((kf * 2 + hi) ^ os) * 8];
        #pragma unroll
        for (int kf = 0; kf < 8; ++kf)
            fa2[kf] = *(const v8h*)&sW2[o * 128 + ((kf * 2 + hi) ^ os) * 8];
    }

    for (int g = 0; g < 4; ++g) {
        // ---- a1: sG1 -> sH1 ----
        #pragma unroll
        for (int rt = 0; rt < 2; ++rt) {
            int r = rt * 32 + ln, rs = r & 7;
            v16f acc;
            #pragma unroll
            for (int i = 0; i < 16; ++i) acc[i] = 0.0f;
            #pragma unroll
            for (int kf = 0; kf < 4; ++kf) {
                v8h fb = *(const v8h*)&sG1[r * 64 + ((kf * 2 + hi) ^ rs) * 8];
                acc = __builtin_amdgcn_mfma_f32_32x32x16_f16(fa[kf], fb, acc, 0, 0, 0);
            }
            #pragma unroll
            for (int q = 0; q < 4; ++q) {
                v4h hv;
                #pragma unroll
                for (int j = 0; j < 4; ++j)
                    hv[j] = (_Float16)fmaxf(acc[q * 4 + j] + bias1[q * 4 + j], 0.0f);
                int gg = w * 4 + q;
                *(v4h*)&sH1[r * 128 + ((gg ^ rs) * 8) + 4 * hi] = hv;
            }
        }
        __syncthreads();

        // prefetch next group's G1 (gather latency overlaps a2 MFMAs)
        if (g < 3) nbr_stage_g1(sG1, Cf, Qf, IDX, t, gpt0, g + 1, base);

        // ---- a2: sH1 -> pooled sPool rows ----
        #pragma unroll
        for (int rt = 0; rt < 2; ++rt) {
            int r = rt * 32 + ln, rs = r & 7;
            v16f acc;
            #pragma unroll
            for (int i = 0; i < 16; ++i) acc[i] = 0.0f;
            #pragma unroll
            for (int kf = 0; kf < 8; ++kf) {
                v8h fb = *(const v8h*)&sH1[r * 128 + ((kf * 2 + hi) ^ rs) * 8];
                acc = __builtin_amdgcn_mfma_f32_32x32x16_f16(fa2[kf], fb, acc, 0, 0, 0);
            }
            #pragma unroll
            for (int i = 0; i < 16; ++i) {
                float v = acc[i];
                v = fmaxf(v, __shfl_xor(v, 1));
                v = fmaxf(v, __shfl_xor(v, 2));
                v = fmaxf(v, __shfl_xor(v, 4));
                v = fmaxf(v, __shfl_xor(v, 8));
                acc[i] = v;
            }
            if ((l & 15) == 0) {
                int p = g * 4 + rt * 2 + ((l >> 4) & 1);
                #pragma unroll
                for (int q = 0; q < 4; ++q) {
                    float4 o4;
                    o4.x = fmaxf(acc[q * 4 + 0] + bias2[q * 4 + 0], 0.0f);
                    o4.y = fmaxf(acc[q * 4 + 1] + bias2[q * 4 + 1], 0.0f);
                    o4.z = fmaxf(acc[q * 4 + 2] + bias2[q * 4 + 2], 0.0f);
                    o4.w = fmaxf(acc[q * 4 + 3] + bias2[q * 4 + 3], 0.0f);
                    int ob = w * 32 + 8 * q + 4 * hi;
                    *(float4*)&sPool[p * 128 + ob] = o4;
                }
            }
        }
        __syncthreads();
    }

    // coalesced burst write: 16 points x 128 ch = 512 float4
    {
        float* LOCAL = ws + LOCAL_OFF;
        const float4* sp4 = (const float4*)sPool;
        #pragma unroll
        for (int u = 0; u < 2; ++u) {
            int e = t + 256 * u;
            int pp = e >> 5, cc = e & 31;
            ((float4*)&LOCAL[(size_t)(gpt0 + pp) * 128])[cc] = sp4[e];
        }
    }
}

// ---------------------------------------------------------------------------
// Kernel 4: global feature = max over N of local.
// ---------------------------------------------------------------------------
__global__ __launch_bounds__(128) void gf_kernel(float* __restrict__ ws)
{
    int b = blockIdx.x, sl = blockIdx.y;
    int c = threadIdx.x;
    const float* LOCAL = ws + LOCAL_OFF + (size_t)(b * 4096 + sl * 128) * 128;
    float m = 0.0f;
    #pragma unroll 4
    for (int i = 0; i < 128; ++i) m = fmaxf(m, LOCAL[i * 128 + c]);
    atomicMax((int*)(ws + GF_OFF) + b * 128 + c, __float_as_int(m));
}

// ---------------------------------------------------------------------------
// Kernel 5: head c2/c3 fp16 MFMA + c4 fp32 (unchanged — verified).
// ---------------------------------------------------------------------------
__global__ __launch_bounds__(256) void head_mfma_kernel(float* __restrict__ ws, float* __restrict__ out)
{
    __shared__ __align__(16) unsigned char smem[66560];
    _Float16* sF  = (_Float16*)smem;
    float*    sF3 = (float*)smem;
    _Float16* sF2 = (_Float16*)(smem + 33792);

    const int t  = threadIdx.x;
    const int l  = t & 63;
    const int w  = t >> 6;
    const int ln = l & 31;
    const int hi = l >> 5;
    const int gpt0 = blockIdx.x * 64;
    const int b = blockIdx.x >> 6;

    const float4* c2h = (const float4*)(ws + C2T_OFF);
    const float4* c3h = (const float4*)(ws + C3H_OFF);

    {
        int m = t >> 2, cs = t & 3;
        const float4* src = (cs < 2)
            ? (const float4*)(ws + LOCAL_OFF + (size_t)(gpt0 + m) * 128) + cs * 16
            : (const float4*)(ws + GF_OFF + b * 128) + (cs - 2) * 16;
        int c0 = cs * 64;
        #pragma unroll
        for (int u = 0; u < 8; ++u) {
            float4 a0 = src[u * 2], a1 = src[u * 2 + 1];
            v8h h;
            h[0] = (_Float16)a0.x; h[1] = (_Float16)a0.y;
            h[2] = (_Float16)a0.z; h[3] = (_Float16)a0.w;
            h[4] = (_Float16)a1.x; h[5] = (_Float16)a1.y;
            h[6] = (_Float16)a1.z; h[7] = (_Float16)a1.w;
            int g = ((c0 >> 3) + u) ^ (m & 31);
            *(v8h*)&sF[m * 256 + g * 8] = h;
        }
    }
    __syncthreads();

    #pragma unroll
    for (int ot = 0; ot < 2; ++ot) {
        int ot2 = 2 * w + ot;
        v8h fa[16];
        #pragma unroll
        for (int s = 0; s < 16; ++s) {
            float4 tmp = c2h[(ot2 * 16 + s) * 64 + l];
            fa[s] = *(v8h*)&tmp;
        }
        float b2[16];
        #pragma unroll
        for (int i = 0; i < 16; ++i)
            b2[i] = ws[BC2_OFF + ot2 * 32 + (i & 3) + 8 * (i >> 2) + 4 * hi];
        #pragma unroll
        for (int mt = 0; mt < 2; ++mt) {
            int m = mt * 32 + ln;
            v16f acc;
            #pragma unroll
            for (int i = 0; i < 16; ++i) acc[i] = 0.0f;
            #pragma unroll
            for (int s = 0; s < 16; ++s) {
                v8h fb = *(const v8h*)&sF[m * 256 + (((2 * s + hi) ^ ln) * 8)];
                acc = __builtin_amdgcn_mfma_f32_32x32x16_f16(fa[s], fb, acc, 0, 0, 0);
            }
            #pragma unroll
            for (int q = 0; q < 4; ++q) {
                v4h hv;
                #pragma unroll
                for (int j = 0; j < 4; ++j)
                    hv[j] = (_Float16)fmaxf(acc[q * 4 + j] + b2[q * 4 + j], 0.0f);
                *(v4h*)&sF2[m * 256 + (((ot2 * 4 + q) ^ ln) * 8) + 4 * hi] = hv;
            }
        }
    }
    __syncthreads();

    {
        v8h fa[16];
        #pragma unroll
        for (int s = 0; s < 16; ++s) {
            float4 tmp = c3h[(w * 16 + s) * 64 + l];
            fa[s] = *(v8h*)&tmp;
        }
        float b3[16];
        #pragma unroll
        for (int i = 0; i < 16; ++i)
            b3[i] = ws[BC3_OFF + w * 32 + (i & 3) + 8 * (i >> 2) + 4 * hi];
        #pragma unroll
        for (int mt = 0; mt < 2; ++mt) {
            int m = mt * 32 + ln;
            v16f acc;
            #pragma unroll
            for (int i = 0; i < 16; ++i) acc[i] = 0.0f;
            #pragma unroll
            for (int s = 0; s < 16; ++s) {
                v8h fb = *(const v8h*)&sF2[m * 256 + (((2 * s + hi) ^ ln) * 8)];
                acc = __builtin_amdgcn_mfma_f32_32x32x16_f16(fa[s], fb, acc, 0, 0, 0);
            }
            #pragma unroll
            for (int q = 0; q < 4; ++q) {
                float4 hv;
                hv.x = fmaxf(acc[q * 4 + 0] + b3[q * 4 + 0], 0.0f);
                hv.y = fmaxf(acc[q * 4 + 1] + b3[q * 4 + 1], 0.0f);
                hv.z = fmaxf(acc[q * 4 + 2] + b3[q * 4 + 2], 0.0f);
                hv.w = fmaxf(acc[q * 4 + 3] + b3[q * 4 + 3], 0.0f);
                *(float4*)&sF3[m * 132 + w * 32 + q * 8 + 4 * hi] = hv;
            }
        }
    }
    __syncthreads();

    const float* C4T = ws + C4T_OFF;
    for (int mo = t; mo < 384; mo += 256) {
        int m = mo / 6, o = mo - m * 6;
        float a = ws[BC4_OFF + o];
        const float4* f4 = (const float4*)(sF3 + m * 132);
        #pragma unroll 8
        for (int kq = 0; kq < 32; ++kq) {
            float4 f = f4[kq];
            a = fmaf(f.x, C4T[(kq * 4 + 0) * 6 + o], a);
            a = fmaf(f.y, C4T[(kq * 4 + 1) * 6 + o], a);
            a = fmaf(f.z, C4T[(kq * 4 + 2) * 6 + o], a);
            a = fmaf(f.w, C4T[(kq * 4 + 3) * 6 + o], a);
        }
        out[(size_t)(gpt0 + m) * 6 + o] = a;
    }
}

// ---------------------------------------------------------------------------
extern "C" void kernel_launch(void* const* d_in, const int* in_sizes, int n_in,
                              void* d_out, int out_size, void* d_ws, size_t ws_size,
                              hipStream_t stream)
{
    const float* pts = (const float*)d_in[0];
    float* ws = (float*)d_ws;
    float* out = (float*)d_out;

    hipMemsetAsync(ws + GF_OFF, 0, 1024 * sizeof(float), stream);

    fold_kernel<<<517, 256, 0, stream>>>(
        (const float*)d_in[1],  (const float*)d_in[2],  (const float*)d_in[3],  (const float*)d_in[4],  (const float*)d_in[5],  (const float*)d_in[6],
        (const float*)d_in[7],  (const float*)d_in[8],  (const float*)d_in[9],  (const float*)d_in[10], (const float*)d_in[11], (const float*)d_in[12],
        (const float*)d_in[13], (const float*)d_in[14], (const float*)d_in[15], (const float*)d_in[16], (const float*)d_in[17], (const float*)d_in[18],
        (const float*)d_in[19], (const float*)d_in[20], (const float*)d_in[21], (const float*)d_in[22], (const float*)d_in[23], (const float*)d_in[24],
        (const float*)d_in[25], (const float*)d_in[26], (const float*)d_in[27], (const float*)d_in[28], (const float*)d_in[29], (const float*)d_in[30],
        (const float*)d_in[31], (const float*)d_in[32], (const float*)d_in[33], (const float*)d_in[34], (const float*)d_in[35], (const float*)d_in[36],
        (const float*)d_in[37], (const float*)d_in[38], (const float*)d_in[39], (const float*)d_in[40], (const float*)d_in[41], (const float*)d_in[42],
        (const float*)d_in[43], (const float*)d_in[44],
        ws);

    point_mlp_kernel<<<8192, 256, 0, stream>>>(pts, ws);
    knn_kernel<<<512, 512, 0, stream>>>(ws);
    nbr_mlp_mfma_kernel<<<2048, 256, 0, stream>>>(ws);
    gf_kernel<<<dim3(8, 32), 128, 0, stream>>>(ws);
    head_mfma_kernel<<<512, 256, 0, stream>>>(ws, out);
}